// Round 15
// baseline (3037.228 us; speedup 1.0000x reference)
//
#include <hip/hip_runtime.h>
#include <cstdint>
#include <cstddef>

#define THREADS 256

typedef _Float16 f16x8 __attribute__((ext_vector_type(8)));
typedef _Float16 f16x4 __attribute__((ext_vector_type(4)));
typedef _Float16 f16x2 __attribute__((ext_vector_type(2)));
typedef float f32x4 __attribute__((ext_vector_type(4)));
typedef float f32x8 __attribute__((ext_vector_type(8)));

__device__ __forceinline__ void gll16(const void* g, void* l) {
    __builtin_amdgcn_global_load_lds(
        (const __attribute__((address_space(1))) unsigned int*)g,
        (__attribute__((address_space(3))) unsigned int*)l, 16, 0, 0);
}

// ---------------------------------------------------------------------------
// Batched scale weight pack (8 weights, convu format). Slots 1-6 used.
// ---------------------------------------------------------------------------
__global__ void pack_scale_all_kernel(
    const float* __restrict__ w0, const float* __restrict__ w1,
    const float* __restrict__ w2, const float* __restrict__ w3,
    const float* __restrict__ w4, const float* __restrict__ w5,
    const float* __restrict__ w6, const float* __restrict__ w7,
    _Float16* __restrict__ wp)
{
    const int wi = blockIdx.y;
    const float* w = (wi == 0) ? w0 : (wi == 1) ? w1 : (wi == 2) ? w2 : (wi == 3) ? w3
                   : (wi == 4) ? w4 : (wi == 5) ? w5 : (wi == 6) ? w6 : w7;
    const int Cin = (wi == 7) ? 260 : 256;
    const int CC  = (wi == 7) ? 9 : 8;
    _Float16* dst = wp + (size_t)wi * 663552;
    int idx = blockIdx.x * THREADS + threadIdx.x;
    int total = 256 * CC * 4;
    if (idx >= total) return;
    int u = idx & 3;
    int cc = (idx >> 2) % CC;
    int co = (idx >> 2) / CC;
    int ci0 = cc * 32 + u * 8;
    for (int tap = 0; tap < 9; ++tap) {
        f16x8 v;
#pragma unroll
        for (int j = 0; j < 8; ++j) {
            int ci = ci0 + j;
            v[j] = (ci < Cin) ? (_Float16)w[((size_t)co * Cin + ci) * 9 + tap] : (_Float16)0.f;
        }
        *reinterpret_cast<f16x8*>(dst + ((((size_t)tap * CC + cc) * 4 + u) * 256 + co) * 8) = v;
    }
}

// ---------------------------------------------------------------------------
// Dense-GEMM weight pack (Cout=256): [t][co(256)x8kc][8], swizzle kc^(co&7).
// ---------------------------------------------------------------------------
__global__ void pack_wdense_kernel(const float* __restrict__ w, _Float16* __restrict__ wp,
                                   int CinTrue, int CINP)
{
    const int NSTEP = 9 * (CINP / 64);
    int idx = blockIdx.x * THREADS + threadIdx.x;
    if (idx >= 256 * NSTEP * 8) return;
    int kc = idx & 7;
    int t = (idx >> 3) % NSTEP;
    int co = (idx >> 3) / NSTEP;
    int kcs = kc ^ (co & 7);
    int k = t * 64 + kcs * 8;
    int tap = k / CINP;
    int cib = k - tap * CINP;
    f16x8 v;
#pragma unroll
    for (int j = 0; j < 8; ++j) {
        int ci = cib + j;
        v[j] = (ci < CinTrue) ? (_Float16)w[((size_t)co * CinTrue + ci) * 9 + tap] : (_Float16)0.f;
    }
    *reinterpret_cast<f16x8*>(wp + ((size_t)t * 2048 + co * 8 + kc) * 8) = v;
}

// ---------------------------------------------------------------------------
// Batched head-GEMM weight pack (8 layers). R15 format: [t][gy(4)][r(128)x8kc][8]
// (gy = co quarter). K tap-major, swizzle kc^(r&7) baked. Same total bytes.
// ---------------------------------------------------------------------------
__global__ void pack_whead_all_kernel(const float* __restrict__ hw0,
                                      const float* __restrict__ hw,
                                      _Float16* __restrict__ wp0,
                                      _Float16* __restrict__ wpH)
{
    const int wi = blockIdx.y;
    const int Cin = (wi == 0) ? 256 : 512;
    const float* w = (wi == 0) ? hw0 : hw + (size_t)(wi - 1) * 2359296;
    _Float16* wp = (wi == 0) ? wp0 : wpH + (size_t)(wi - 1) * 2359296;
    const int NSTEP = 9 * (Cin / 64);
    int idx = blockIdx.x * THREADS + threadIdx.x;
    int total = 512 * NSTEP * 8;
    if (idx >= total) return;
    int kc = idx & 7;
    int t = (idx >> 3) % NSTEP;
    int co = (idx >> 3) / NSTEP;
    int gy = co >> 7;                  // co quarter (0..3)
    int r = co & 127;
    int kcs = kc ^ (r & 7);
    int k = t * 64 + kcs * 8;
    int tap = k / Cin;
    int cib = k - tap * Cin;
    f16x8 v;
#pragma unroll
    for (int j = 0; j < 8; ++j)
        v[j] = (_Float16)w[((size_t)co * Cin + cib + j) * 9 + tap];
    *reinterpret_cast<f16x8*>(wp + ((size_t)(t * 4 + gy) * 1024 + r * 8 + kc) * 8) = v;
}

__global__ void zerows_kernel(float* __restrict__ p)
{
    p[blockIdx.x * THREADS + threadIdx.x] = 0.f;
}

// Zero pingA and pingB (4x16384x512 f16 each) so inactive rows are exactly 0.
__global__ void zero2_kernel(_Float16* __restrict__ a, _Float16* __restrict__ b)
{
    const size_t N = 4ull * 16384 * 512;
    for (size_t i = ((size_t)blockIdx.x * THREADS + threadIdx.x) * 8; i < N;
         i += (size_t)gridDim.x * THREADS * 8) {
        *reinterpret_cast<f16x8*>(a + i) = (f16x8){};
        *reinterpret_cast<f16x8*>(b + i) = (f16x8){};
    }
}

// ---------------------------------------------------------------------------
// Deterministic active-pixel compaction: fg [4*16384] int -> list[40960] int.
// R15: consumed in 160 tiles of 256 entries (capacity unchanged).
// ---------------------------------------------------------------------------
__global__ __launch_bounds__(1024)
void compact_kernel(const int* __restrict__ fg, int* __restrict__ list)
{
    __shared__ int part[1024];
    const int tid = threadIdx.x;
    const int base = tid * 64;
    int cnt = 0;
    for (int j = 0; j < 64; ++j) cnt += (fg[base + j] > 0) ? 1 : 0;
    part[tid] = cnt;
    __syncthreads();
    for (int off = 1; off < 1024; off <<= 1) {
        int v = (tid >= off) ? part[tid - off] : 0;
        __syncthreads();
        part[tid] += v;
        __syncthreads();
    }
    int pos = part[tid] - cnt;
    for (int j = 0; j < 64; ++j)
        if (fg[base + j] > 0) list[pos++] = base + j;
    const int total = part[1023];
    for (int i = total + tid; i < 40960; i += 1024) list[i] = -1;
}

// ---------------------------------------------------------------------------
// Batched NCHW fp32 -> NHWC fp16 transpose, all 4 FPN levels in one launch.
// ---------------------------------------------------------------------------
__global__ __launch_bounds__(256)
void t_all_kernel(const float* __restrict__ s2, const float* __restrict__ s3,
                  const float* __restrict__ s4, const float* __restrict__ s5,
                  _Float16* __restrict__ d2, _Float16* __restrict__ d3,
                  _Float16* __restrict__ d4, _Float16* __restrict__ d5)
{
    __shared__ _Float16 tile[64 * 32];
    const int lvl = blockIdx.z >> 2;
    const int n = blockIdx.z & 3;
    const int HW = 16384 >> (2 * lvl);
    const int p0 = blockIdx.x * 64;
    if (p0 >= HW) return;
    const float* in = (lvl == 0) ? s2 : (lvl == 1) ? s3 : (lvl == 2) ? s4 : s5;
    _Float16* out = (lvl == 0) ? d2 : (lvl == 1) ? d3 : (lvl == 2) ? d4 : d5;
    const int C = 256;
    const int c0 = blockIdx.y * 32;
    const int tid = threadIdx.x;
    {
        int ci = tid >> 3;
        int j8 = (tid & 7) * 8;
        f32x8 v = *reinterpret_cast<const f32x8*>(in + ((size_t)n * C + c0 + ci) * HW + p0 + j8);
#pragma unroll
        for (int j = 0; j < 8; ++j)
            tile[(j8 + j) * 32 + ci] = (_Float16)v[j];
    }
    __syncthreads();
    {
        int px = tid >> 2;
        int u = tid & 3;
        f16x8 v = *reinterpret_cast<const f16x8*>(&tile[px * 32 + u * 8]);
        *reinterpret_cast<f16x8*>(out + ((size_t)n * HW + p0 + px) * C + c0 + u * 8) = v;
    }
}

// ---------------------------------------------------------------------------
// Unified conv -- kept for the small scale convs (64^2/32^2/16^2, slots 1-6).
// ---------------------------------------------------------------------------
template<int INF32, int OUTMODE, int CC>
__global__ __launch_bounds__(512, 4)
void convu_kernel(const void* __restrict__ inv, const _Float16* __restrict__ wp,
                  const float* __restrict__ bias, const int* __restrict__ msk,
                  void* __restrict__ outp, int Cout, int H, int W,
                  int inCst, int outCst, int useMask)
{
    __shared__ _Float16 Xs[2 * 1344 * 8];

    const int tid = threadIdx.x;
    const int lane = tid & 63;
    const int wave = tid >> 6;
    const int lm = lane & 15;
    const int lu = lane >> 4;
    const int waveco = (wave & 1) * 64;
    const int wrow = (wave >> 1) * 4;
    const int n = blockIdx.z;
    const int co0 = blockIdx.y * 128;
    const int tpr = W >> 4;
    const int tx = blockIdx.x % tpr;
    const int ty = blockIdx.x / tpr;
    const int x0 = tx << 4;
    const int y0 = ty << 4;
    const int HW = H * W;

    int soff[3];
#pragma unroll
    for (int t = 0; t < 3; ++t) {
        int s = tid + t * 512;
        int item = s >> 2, u = s & 3;
        int row = item / 18, col = item - row * 18;
        int y = y0 + row - 1, x = x0 + col - 1;
        soff[t] = (s < 1296 && y >= 0 && y < H && x >= 0 && x < W)
                      ? ((n * HW + y * W + x) * inCst + u * 8) : -1;
    }

    f32x4 acc[4][4];
#pragma unroll
    for (int m = 0; m < 4; ++m)
#pragma unroll
        for (int nf = 0; nf < 4; ++nf)
            acc[m][nf] = (f32x4){0.f, 0.f, 0.f, 0.f};

    const size_t tstride = (size_t)CC * 4 * Cout * 8;

    {
        const _Float16* src = (const _Float16*)inv;
#pragma unroll
        for (int t = 0; t < 3; ++t) {
            int s = tid + t * 512;
            if (s < 1296 && soff[t] < 0) {
                *reinterpret_cast<f16x8*>(&Xs[s * 8]) = (f16x8){};
                *reinterpret_cast<f16x8*>(&Xs[(1344 + s) * 8]) = (f16x8){};
            }
        }
#pragma unroll
        for (int t = 0; t < 3; ++t) {
            int s = tid + t * 512;
            if (s < 1296 && soff[t] >= 0)
                gll16(src + soff[t], &Xs[(t * 512 + (tid & ~63)) * 8]);
        }
    }
    __syncthreads();

    int bsel = 0;
    for (int cc = 0; cc < CC; ++cc) {
        if (cc + 1 < CC) {
            const _Float16* src = (const _Float16*)inv;
#pragma unroll
            for (int t = 0; t < 3; ++t) {
                int s = tid + t * 512;
                if (s < 1296 && soff[t] >= 0)
                    gll16(src + soff[t] + (cc + 1) * 32,
                          &Xs[((bsel ^ 1) * 1344 + t * 512 + (tid & ~63)) * 8]);
            }
        }
        {
            const int xbase = bsel * 1344;
            const _Float16* wb = wp + (((size_t)cc * 4 + lu) * Cout + co0 + waveco + lm) * 8;
#pragma unroll
            for (int tap = 0; tap < 9; ++tap) {
                const int dy = tap / 3, dx = tap % 3;
                const _Float16* wt = wb + (size_t)tap * tstride;
                f16x8 a[4], b[4];
#pragma unroll
                for (int m = 0; m < 4; ++m)
                    a[m] = *reinterpret_cast<const f16x8*>(wt + m * 128);
#pragma unroll
                for (int nf = 0; nf < 4; ++nf) {
                    int slot = ((wrow + nf + dy) * 18 + lm + dx) * 4 + lu;
                    b[nf] = *reinterpret_cast<const f16x8*>(&Xs[(xbase + slot) * 8]);
                }
#pragma unroll
                for (int m = 0; m < 4; ++m)
#pragma unroll
                    for (int nf = 0; nf < 4; ++nf)
                        acc[m][nf] = __builtin_amdgcn_mfma_f32_16x16x32_f16(a[m], b[nf], acc[m][nf], 0, 0, 0);
            }
        }
        __syncthreads();
        bsel ^= 1;
    }

    const int xE = x0 + lm;
    const size_t nHW = (size_t)n * HW;
#pragma unroll
    for (int nf = 0; nf < 4; ++nf) {
        const int y = y0 + wrow + nf;
        float mv = 1.f;
        if (useMask) mv = (msk[nHW + y * W + xE] > 0) ? 1.f : 0.f;
        const size_t pixo = (nHW + (size_t)y * W + xE) * outCst;
#pragma unroll
        for (int m = 0; m < 4; ++m) {
            const int cb = co0 + waveco + m * 16 + lu * 4;
            const f32x4 bv = *reinterpret_cast<const f32x4*>(bias + cb);
            if (OUTMODE == 0) {
                f16x4 h;
#pragma unroll
                for (int r = 0; r < 4; ++r)
                    h[r] = (_Float16)(fmaxf(acc[m][nf][r] + bv[r], 0.f) * mv);
                *reinterpret_cast<f16x4*>((_Float16*)outp + pixo + cb) = h;
            } else if (OUTMODE == 1) {
                f32x4 v;
#pragma unroll
                for (int r = 0; r < 4; ++r)
                    v[r] = fmaxf(acc[m][nf][r] + bv[r], 0.f);
                *reinterpret_cast<f32x4*>((float*)outp + pixo + cb) = v;
            } else {
                f32x4 old = *reinterpret_cast<const f32x4*>((float*)outp + pixo + cb);
#pragma unroll
                for (int r = 0; r < 4; ++r)
                    old[r] += fmaxf(acc[m][nf][r] + bv[r], 0.f);
                *reinterpret_cast<f32x4*>((float*)outp + pixo + cb) = old;
            }
        }
    }
}

// ---------------------------------------------------------------------------
// DENSE conv as LDS-staged GEMM tile (p2 + comb @128^2). Unchanged from R14.
// ---------------------------------------------------------------------------
template<int CINP, int MASK>
__global__ __launch_bounds__(512, 1)
void gemm_dense_kernel(const _Float16* __restrict__ in,
                       const _Float16* __restrict__ wpk,
                       const float* __restrict__ bias,
                       const int* __restrict__ fg,
                       _Float16* __restrict__ outp, int outCst,
                       const _Float16* __restrict__ zpage)
{
    constexpr int SPT = CINP / 64;
    __shared__ __attribute__((aligned(16))) char ldsb[2 * 65536];  // 128 KB

    const int job = blockIdx.x;        // 0..255
    const int xcd = job & 7;
    const int idx = job >> 3;          // 0..31
    const int img = idx >> 3;          // 0..3
    const int tile = xcd * 8 + (idx & 7);
    const int x0 = (tile & 7) << 4;
    const int y0 = (tile >> 3) << 4;

    const int tid = threadIdx.x;
    const int lane = tid & 63;
    const int wave = tid >> 6;
    const int lm = lane & 15;
    const int lu = lane >> 4;
    const int wco = (wave & 1) * 128;
    const int wpx = (wave >> 1) * 64;

    const _Float16* bsrc = in + (size_t)img * 16384 * CINP;

    const _Float16* bptr[4];
    unsigned long long inbm = 0;
    int dstA[4], dstB[4];
#pragma unroll
    for (int s = 0; s < 4; ++s) {
        const int row = s * 64 + (tid >> 3);   // 0..255
        const int kc = (tid & 7) ^ (row & 7);
        const int y = y0 + (row >> 4);
        const int x = x0 + (row & 15);
        bptr[s] = bsrc + (size_t)(y * 128 + x) * CINP + kc * 8;
#pragma unroll
        for (int tap = 0; tap < 9; ++tap) {
            const int yy = y + tap / 3 - 1;
            const int xx = x + tap % 3 - 1;
            if ((unsigned)yy < 128u && (unsigned)xx < 128u)
                inbm |= 1ull << (s * 9 + tap);
        }
        dstA[s] = (s * 512 + (tid & ~63)) * 16;
        dstB[s] = 32768 + (s * 512 + (tid & ~63)) * 16;
    }

    auto STAGE = [&](int t, int bufByte) {
        const _Float16* as = wpk + (size_t)t * 16384;
#pragma unroll
        for (int s = 0; s < 4; ++s)
            gll16(as + (size_t)(s * 512 + tid) * 8, ldsb + bufByte + dstA[s]);
        const int tap = t / SPT;
        const int ci0 = (t % SPT) * 64;
        const int delta = ((tap / 3 - 1) * 128 + (tap % 3 - 1)) * CINP + ci0;
#pragma unroll
        for (int s = 0; s < 4; ++s) {
            const bool ok = (inbm >> (s * 9 + tap)) & 1ull;
            const _Float16* src = ok ? (bptr[s] + delta) : zpage;
            gll16(src, ldsb + bufByte + dstB[s]);
        }
    };

    f32x4 acc[8][4];
#pragma unroll
    for (int m = 0; m < 8; ++m)
#pragma unroll
        for (int n = 0; n < 4; ++n)
            acc[m][n] = (f32x4){0.f, 0.f, 0.f, 0.f};

    STAGE(0, 0);
    __syncthreads();

    int bsel = 0;
    for (int cb = 0; cb < SPT; ++cb) {
        for (int tap = 0; tap < 9; ++tap) {
            if (tap < 8) STAGE((tap + 1) * SPT + cb, (bsel ^ 1) * 65536);
            else if (cb + 1 < SPT) STAGE(cb + 1, (bsel ^ 1) * 65536);
            const int ab = bsel * 65536;
#pragma unroll
            for (int s = 0; s < 2; ++s) {
                f16x8 bfr[4];
#pragma unroll
                for (int n = 0; n < 4; ++n) {
                    const int row = wpx + n * 16 + lm;
                    const int ch = (s * 4 + lu) ^ (row & 7);
                    bfr[n] = *reinterpret_cast<const f16x8*>(ldsb + ab + 32768 + row * 128 + ch * 16);
                }
#pragma unroll
                for (int m = 0; m < 8; ++m) {
                    const int row = wco + m * 16 + lm;
                    const int ch = (s * 4 + lu) ^ (row & 7);
                    const f16x8 afr = *reinterpret_cast<const f16x8*>(ldsb + ab + row * 128 + ch * 16);
#pragma unroll
                    for (int n = 0; n < 4; ++n)
                        acc[m][n] = __builtin_amdgcn_mfma_f32_16x16x32_f16(afr, bfr[n], acc[m][n], 0, 0, 0);
                }
            }
            __syncthreads();
            bsel ^= 1;
        }
    }

    const int base = img * 16384;
#pragma unroll
    for (int n = 0; n < 4; ++n) {
        const int px = wpx + n * 16 + lm;
        const int y = y0 + (px >> 4), x = x0 + (px & 15);
        float mv = 1.f;
        if (MASK) mv = (fg[base + y * 128 + x] > 0) ? 1.f : 0.f;
        _Float16* pp = outp + ((size_t)base + y * 128 + x) * outCst + wco;
#pragma unroll
        for (int m = 0; m < 8; ++m) {
            const f32x4 bv = *reinterpret_cast<const f32x4*>(bias + wco + m * 16 + lu * 4);
            f16x4 h;
#pragma unroll
            for (int rr = 0; rr < 4; ++rr)
                h[rr] = (_Float16)(fmaxf(acc[m][n][rr] + bv[rr], 0.f) * mv);
            *reinterpret_cast<f16x4*>(pp + m * 16 + lu * 4) = h;
        }
    }
}

// ---------------------------------------------------------------------------
// SPARSE head conv as gather-GEMM. R15: tile 128co x 256px, single 48KB LDS
// buffer -> 2 blocks/CU (launch_bounds(512,4), acc=64 VGPR; cross-block
// overlap hides stage/barrier stalls per m114). Grid 640 (160 tiles x 4 gy),
// active ~516 = ~1 round at 2/CU. 8 waves = 2 co-halves(64) x 4 px-grp(64).
// ---------------------------------------------------------------------------
template<int CIN>
__global__ __launch_bounds__(512, 4)
void gemm_head_kernel(const _Float16* __restrict__ in,
                      const _Float16* __restrict__ wpk,
                      const float* __restrict__ bias,
                      const int* __restrict__ list,
                      _Float16* __restrict__ outp,
                      const _Float16* __restrict__ zpage)
{
    constexpr int SPT = CIN / 64;
    __shared__ __attribute__((aligned(16))) char ldsb[49152];  // 48 KB: A 16K + B 32K

    const int job = blockIdx.x;        // 0..639
    const int xcd = job & 7;
    const int r8 = job >> 3;           // 0..79
    const int tile = xcd * 20 + (r8 >> 2);   // 160 tiles, 20 per XCD
    const int gy = r8 & 3;                   // co quarter
    if (list[tile * 256] < 0) return;        // empty tile

    const int tid = threadIdx.x;
    const int lane = tid & 63;
    const int wave = tid >> 6;
    const int lm = lane & 15;
    const int lu = lane >> 4;
    const int wco = (wave & 1) * 64;
    const int g64 = (wave >> 1) * 64;
    const int co0 = gy * 128;

    // ---- per-thread staging state: 4 B row-slots, 2 A slots ----
    const _Float16* bptr[4];
    unsigned long long inbm = 0;
#pragma unroll
    for (int s = 0; s < 4; ++s) {
        const int row = s * 64 + (tid >> 3);          // 0..255
        const int kc = (tid & 7) ^ (row & 7);
        const int entry = list[tile * 256 + row];
        bptr[s] = zpage;
        if (entry >= 0) {
            const int y = (entry >> 7) & 127;
            const int x = entry & 127;
            bptr[s] = in + (size_t)entry * CIN + kc * 8;
#pragma unroll
            for (int tap = 0; tap < 9; ++tap) {
                const int yy = y + tap / 3 - 1;
                const int xx = x + tap % 3 - 1;
                if ((unsigned)yy < 128u && (unsigned)xx < 128u)
                    inbm |= 1ull << (s * 9 + tap);
            }
        }
    }
    const int ldst = (tid & ~63) * 16;   // wave-uniform LDS base component

    auto STAGE = [&](int t) {
        const _Float16* as = wpk + (size_t)(t * 4 + gy) * 8192;
        gll16(as + (size_t)tid * 8, ldsb + ldst);
        gll16(as + (size_t)(512 + tid) * 8, ldsb + 8192 + ldst);
        const int tap = t / SPT;
        const int ci0 = (t % SPT) * 64;
        const int delta = ((tap / 3 - 1) * 128 + (tap % 3 - 1)) * CIN + ci0;
#pragma unroll
        for (int s = 0; s < 4; ++s) {
            const bool ok = (inbm >> (s * 9 + tap)) & 1ull;
            const _Float16* src = ok ? (bptr[s] + delta) : zpage;
            gll16(src, ldsb + 16384 + s * 8192 + ldst);
        }
    };

    f32x4 acc[4][4];
#pragma unroll
    for (int m = 0; m < 4; ++m)
#pragma unroll
        for (int n = 0; n < 4; ++n)
            acc[m][n] = (f32x4){0.f, 0.f, 0.f, 0.f};

    for (int cb = 0; cb < SPT; ++cb) {
        for (int tap = 0; tap < 9; ++tap) {
            STAGE(tap * SPT + cb);
            __syncthreads();   // drains this block's loads (vmcnt0 at barrier)
#pragma unroll
            for (int s = 0; s < 2; ++s) {
                f16x8 bfr[4];
#pragma unroll
                for (int n = 0; n < 4; ++n) {
                    const int row = g64 + n * 16 + lm;
                    const int ch = (s * 4 + lu) ^ (row & 7);
                    bfr[n] = *reinterpret_cast<const f16x8*>(ldsb + 16384 + row * 128 + ch * 16);
                }
#pragma unroll
                for (int m = 0; m < 4; ++m) {
                    const int row = wco + m * 16 + lm;
                    const int ch = (s * 4 + lu) ^ (row & 7);
                    const f16x8 afr = *reinterpret_cast<const f16x8*>(ldsb + row * 128 + ch * 16);
#pragma unroll
                    for (int n = 0; n < 4; ++n)
                        acc[m][n] = __builtin_amdgcn_mfma_f32_16x16x32_f16(afr, bfr[n], acc[m][n], 0, 0, 0);
                }
            }
            __syncthreads();   // all reads done before next STAGE overwrites
        }
    }

    // ---- epilogue: scatter active rows, bias+relu ----
#pragma unroll
    for (int n = 0; n < 4; ++n) {
        const int entry = list[tile * 256 + g64 + n * 16 + lm];
        if (entry < 0) continue;
        _Float16* pp = outp + (size_t)entry * 512 + co0 + wco;
#pragma unroll
        for (int m = 0; m < 4; ++m) {
            const f32x4 bv = *reinterpret_cast<const f32x4*>(bias + co0 + wco + m * 16 + lu * 4);
            f16x4 h;
#pragma unroll
            for (int rr = 0; rr < 4; ++rr)
                h[rr] = (_Float16)fmaxf(acc[m][n][rr] + bv[rr], 0.f);
            *reinterpret_cast<f16x4*>(pp + m * 16 + lu * 4) = h;
        }
    }
}

// ---------------------------------------------------------------------------
// fp16 NHWC 2x bilinear upsample (align_corners=False -> clamped 0.75/0.25).
// ---------------------------------------------------------------------------
__global__ void up2h_kernel(const _Float16* __restrict__ in, _Float16* __restrict__ out,
                            int Hin, int Win)
{
    const int Wout = Win << 1, Hout = Hin << 1;
    const int lw = __ffs(Wout) - 1, lh = __ffs(Hout) - 1;
    int i = blockIdx.x * THREADS + threadIdx.x;
    if (i >= 4 * Hout * Wout * 32) return;
    int u = i & 31;
    int p = i >> 5;
    int x = p & (Wout - 1);
    int y = (p >> lw) & (Hout - 1);
    int n = p >> (lw + lh);
    int iy = y >> 1, ix = x >> 1;
    int y2 = (y & 1) ? min(iy + 1, Hin - 1) : max(iy - 1, 0);
    int x2 = (x & 1) ? min(ix + 1, Win - 1) : max(ix - 1, 0);
    const _Float16* base = in + ((size_t)n * Hin * Win) * 256 + u * 8;
    f16x8 v00 = *reinterpret_cast<const f16x8*>(base + (iy * Win + ix) * 256);
    f16x8 v01 = *reinterpret_cast<const f16x8*>(base + (iy * Win + x2) * 256);
    f16x8 v10 = *reinterpret_cast<const f16x8*>(base + (y2 * Win + ix) * 256);
    f16x8 v11 = *reinterpret_cast<const f16x8*>(base + (y2 * Win + x2) * 256);
    f16x8 o;
#pragma unroll
    for (int j = 0; j < 8; ++j) {
        float v = 0.5625f * (float)v00[j] + 0.1875f * ((float)v01[j] + (float)v10[j])
                + 0.0625f * (float)v11[j];
        o[j] = (_Float16)v;
    }
    *reinterpret_cast<f16x8*>(out + (((size_t)n * Hout * Wout) + y * Wout + x) * 256 + u * 8) = o;
}

// fp32 NHWC 64^2 t64sum -> 128^2 upsample-ADD into fp16 Xch (stride 320, ch 0..255).
__global__ void up2addh_kernel(const float* __restrict__ in, _Float16* __restrict__ Xch)
{
    int i = blockIdx.x * THREADS + threadIdx.x;
    if (i >= 4 * 16384 * 32) return;
    int u = i & 31;
    int p = i >> 5;
    int x = p & 127;
    int y = (p >> 7) & 127;
    int n = p >> 14;
    int iy = y >> 1, ix = x >> 1;
    int y2 = (y & 1) ? min(iy + 1, 63) : max(iy - 1, 0);
    int x2 = (x & 1) ? min(ix + 1, 63) : max(ix - 1, 0);
    const float* base = in + ((size_t)n * 4096) * 256 + u * 8;
    f32x8 v00 = *reinterpret_cast<const f32x8*>(base + (iy * 64 + ix) * 256);
    f32x8 v01 = *reinterpret_cast<const f32x8*>(base + (iy * 64 + x2) * 256);
    f32x8 v10 = *reinterpret_cast<const f32x8*>(base + (y2 * 64 + ix) * 256);
    f32x8 v11 = *reinterpret_cast<const f32x8*>(base + (y2 * 64 + x2) * 256);
    _Float16* dst = Xch + ((size_t)n * 16384 + y * 128 + x) * 320 + u * 8;
    f16x8 d = *reinterpret_cast<const f16x8*>(dst);
#pragma unroll
    for (int j = 0; j < 8; ++j)
        d[j] = (_Float16)((float)d[j] + 0.5625f * v00[j]
               + 0.1875f * (v01[j] + v10[j]) + 0.0625f * v11[j]);
    *reinterpret_cast<f16x8*>(dst) = d;
}

// Coords into fp16 Xch (stride 320) channels 256..259; zero channels 260..319.
__global__ void coords2h_kernel(const float* __restrict__ rel, const float* __restrict__ abs_,
                                _Float16* __restrict__ Xch)
{
    int i = blockIdx.x * THREADS + threadIdx.x;
    if (i >= 4 * 16384) return;
    int px = i & 16383;
    int n = i >> 14;
    _Float16* dst = Xch + ((size_t)n * 16384 + px) * 320 + 256;
    f16x8 v0 = (f16x8){};
    v0[0] = (_Float16)rel[((size_t)n * 2 + 0) * 16384 + px];
    v0[1] = (_Float16)rel[((size_t)n * 2 + 1) * 16384 + px];
    v0[2] = (_Float16)abs_[((size_t)n * 2 + 0) * 16384 + px];
    v0[3] = (_Float16)abs_[((size_t)n * 2 + 1) * 16384 + px];
    *reinterpret_cast<f16x8*>(dst) = v0;
#pragma unroll
    for (int b = 1; b < 8; ++b)
        *reinterpret_cast<f16x8*>(dst + b * 8) = (f16x8){};
}

// 1x1 predictor: NHWC fp16 [n][16384][512] -> NCHW fp32 [n][75][16384].
__global__ __launch_bounds__(256)
void predh_kernel(const _Float16* __restrict__ in, const float* __restrict__ w,
                  const float* __restrict__ bias, float* __restrict__ out)
{
    __shared__ _Float16 lw[25 * 512];
    const int co0 = blockIdx.y * 25;
    const int n = blockIdx.z;
    for (int idx = threadIdx.x; idx < 25 * 512; idx += 256)
        lw[idx] = (_Float16)w[(size_t)(co0 + idx / 512) * 512 + (idx & 511)];
    __syncthreads();
    int px = blockIdx.x * 256 + threadIdx.x;
    const _Float16* ip = in + ((size_t)n * 16384 + px) * 512;
    float acc[25];
#pragma unroll
    for (int j = 0; j < 25; ++j) acc[j] = bias[co0 + j];
    for (int g = 0; g < 64; ++g) {
        union { f16x8 v; f16x2 p[4]; } xv;
        xv.v = *reinterpret_cast<const f16x8*>(ip + g * 8);
#pragma unroll
        for (int j = 0; j < 25; ++j) {
            union { f16x8 v; f16x2 p[4]; } wv;
            wv.v = *reinterpret_cast<const f16x8*>(&lw[j * 512 + g * 8]);
#if __has_builtin(__builtin_amdgcn_fdot2)
#pragma unroll
            for (int k = 0; k < 4; ++k)
                acc[j] = __builtin_amdgcn_fdot2(xv.p[k], wv.p[k], acc[j], false);
#else
#pragma unroll
            for (int k = 0; k < 8; ++k)
                acc[j] = fmaf((float)xv.v[k], (float)wv.v[k], acc[j]);
#endif
        }
    }
    float* op = out + ((size_t)n * 75) * 16384 + px;
#pragma unroll
    for (int j = 0; j < 25; ++j)
        op[(size_t)(co0 + j) * 16384] = acc[j];
}

extern "C" void kernel_launch(void* const* d_in, const int* in_sizes, int n_in,
                              void* d_out, int out_size, void* d_ws, size_t ws_size,
                              hipStream_t stream)
{
    const float* p2   = (const float*)d_in[0];
    const float* p3   = (const float*)d_in[1];
    const float* p4   = (const float*)d_in[2];
    const float* p5   = (const float*)d_in[3];
    const float* rel  = (const float*)d_in[4];
    const float* abs_ = (const float*)d_in[5];
    const int*   fg   = (const int*)d_in[6];
    const float* w_p2_0 = (const float*)d_in[7];
    const float* b_p2_0 = (const float*)d_in[8];
    const float* w_p3_0 = (const float*)d_in[9];
    const float* b_p3_0 = (const float*)d_in[10];
    const float* w_p4_0 = (const float*)d_in[11];
    const float* b_p4_0 = (const float*)d_in[12];
    const float* w_p4_1 = (const float*)d_in[13];
    const float* b_p4_1 = (const float*)d_in[14];
    const float* w_p5_0 = (const float*)d_in[15];
    const float* b_p5_0 = (const float*)d_in[16];
    const float* w_p5_1 = (const float*)d_in[17];
    const float* b_p5_1 = (const float*)d_in[18];
    const float* w_p5_2 = (const float*)d_in[19];
    const float* b_p5_2 = (const float*)d_in[20];
    const float* comb_w = (const float*)d_in[21];
    const float* comb_b = (const float*)d_in[22];
    const float* head_w0 = (const float*)d_in[23];
    const float* head_b0 = (const float*)d_in[24];
    const float* head_w  = (const float*)d_in[25];
    const float* head_b  = (const float*)d_in[26];
    const float* pred_w  = (const float*)d_in[27];
    const float* pred_b  = (const float*)d_in[28];

    // Workspace layout (float offsets). Total 58,704,896 floats = 234.8 MB.
    // Identical to R14 (head pack format changed internally, same bytes).
    float* ws = (float*)d_ws;
    _Float16* Xch     = (_Float16*)ws;                       // 10,485,760 fl as f16 (stride 320)
    _Float16* pingA   = (_Float16*)ws;                       // aliases Xch (dead after comb)
    _Float16* pingB   = (_Float16*)(ws + 18874368);          // 16,777,216 fl
    float*    regD    = ws + 35651584;                       //  8,388,608 fl
    _Float16* p2h     = (_Float16*)regD;
    _Float16* combOut = (_Float16*)regD;
    float*    t64sum  = regD;
    _Float16* t64b    = (_Float16*)(regD + 4194304);
    _Float16* t64c    = (_Float16*)(regD + 5242880);
    _Float16* t32a    = (_Float16*)(regD + 6291456);
    _Float16* t32b    = (_Float16*)(regD + 6553600);
    _Float16* t32c    = (_Float16*)(regD + 6815744);
    _Float16* t16a    = (_Float16*)(regD + 7077888);
    _Float16* p3h     = (_Float16*)(ws + 44040192);          //  2,097,152 fl
    _Float16* p4h     = (_Float16*)(ws + 46137344);          //    524,288 fl
    _Float16* p5h     = (_Float16*)(ws + 46661632);          //    131,072 fl
    _Float16* wpScale = (_Float16*)(ws + 46792704);          //  2,654,208 fl (8 x 663,552 f16)
    float*    zpage   = ws + 49446912;                       //      1,024 fl (4 KB zeros)
    _Float16* wpH0    = (_Float16*)(ws + 49447936);          //    589,824 fl (1,179,648 f16)
    _Float16* wpH     = (_Float16*)(ws + 50037760);          //  8,257,536 fl (7 x 2,359,296 f16)
    int*      actList = (int*)(ws + 58295296);               //     40,960 ints
    _Float16* wpComb  = (_Float16*)(ws + 58336256);          //    368,640 fl (737,280 f16)
    _Float16* wpDp2   = wpScale;                             // dense p2 pack reuses slot 0

    auto wpS = [&](int i) { return wpScale + (size_t)i * 663552; };

    auto convu = [&](const void* in, const _Float16* wpk, const float* bs, void* outp,
                     int mode, int Cout, int H, int W,
                     int inCst, int outCst) {
        dim3 grid((W / 16) * (H / 16), Cout / 128, 4);
        dim3 blk(512);
        if (mode == 0)
            convu_kernel<0, 0, 8><<<grid, blk, 0, stream>>>(in, wpk, bs, fg, outp, Cout, H, W, inCst, outCst, 0);
        else if (mode == 1)
            convu_kernel<0, 1, 8><<<grid, blk, 0, stream>>>(in, wpk, bs, fg, outp, Cout, H, W, inCst, outCst, 0);
        else
            convu_kernel<0, 2, 8><<<grid, blk, 0, stream>>>(in, wpk, bs, fg, outp, Cout, H, W, inCst, outCst, 0);
    };
    auto up2h = [&](const _Float16* in, _Float16* out, int Hin, int Win) {
        int total = 4 * (Hin * 2) * (Win * 2) * 32;
        up2h_kernel<<<dim3((total + THREADS - 1) / THREADS), dim3(THREADS), 0, stream>>>(
            in, out, Hin, Win);
    };

    // ---- batched packs + zero-page + compaction + batched transposes ----
    zerows_kernel<<<dim3(4), dim3(THREADS), 0, stream>>>(zpage);
    compact_kernel<<<dim3(1), dim3(1024), 0, stream>>>(fg, actList);
    pack_scale_all_kernel<<<dim3(36, 8), dim3(THREADS), 0, stream>>>(
        w_p2_0, w_p3_0, w_p4_0, w_p4_1, w_p5_0, w_p5_1, w_p5_2, comb_w, wpScale);
    pack_wdense_kernel<<<dim3(288), dim3(THREADS), 0, stream>>>(w_p2_0, wpDp2, 256, 256);
    pack_wdense_kernel<<<dim3(360), dim3(THREADS), 0, stream>>>(comb_w, wpComb, 260, 320);
    pack_whead_all_kernel<<<dim3(1152, 8), dim3(THREADS), 0, stream>>>(
        head_w0, head_w, wpH0, wpH);
    t_all_kernel<<<dim3(256, 8, 16), dim3(256), 0, stream>>>(
        p2, p3, p4, p5, p2h, p3h, p4h, p5h);

    // ---- p2 scale head -> Xch (fp16 NHWC-320, dense GEMM tile), coords ----
    gemm_dense_kernel<256, 0><<<dim3(256), dim3(512), 0, stream>>>(
        p2h, wpDp2, b_p2_0, fg, Xch, 320, (const _Float16*)zpage);
    coords2h_kernel<<<dim3(256), dim3(THREADS), 0, stream>>>(rel, abs_, Xch);

    // ---- p3 -> t64sum (fp32 write) ----
    convu(p3h, wpS(1), b_p3_0, t64sum, 1, 256, 64, 64, 256, 256);

    // ---- p4 chain: conv32 -> up -> conv64 (fp32 add into t64sum) ----
    convu(p4h, wpS(2), b_p4_0, t32a, 0, 256, 32, 32, 256, 256);
    up2h(t32a, t64b, 32, 32);
    convu(t64b, wpS(3), b_p4_1, t64sum, 2, 256, 64, 64, 256, 256);

    // ---- p5 chain: conv16 -> up -> conv32 -> up -> conv64 (fp32 add) ----
    convu(p5h, wpS(4), b_p5_0, t16a, 0, 256, 16, 16, 256, 256);
    up2h(t16a, t32b, 16, 16);
    convu(t32b, wpS(5), b_p5_1, t32c, 0, 256, 32, 32, 256, 256);
    up2h(t32c, t64c, 32, 32);
    convu(t64c, wpS(6), b_p5_2, t64sum, 2, 256, 64, 64, 256, 256);

    // ---- single upsample-add of merged 64^2 sum into fp16 Xch (stride 320) ----
    up2addh_kernel<<<dim3(8192), dim3(THREADS), 0, stream>>>(t64sum, Xch);

    // ---- comb conv (Xch fp16 NHWC-320 -> combOut fp16 NHWC-256), dense GEMM ----
    gemm_dense_kernel<320, 1><<<dim3(256), dim3(512), 0, stream>>>(
        Xch, wpComb, comb_b, fg, combOut, 256, (const _Float16*)zpage);

    // ---- zero ping buffers (Xch dead now; inactive rows must be exactly 0) ----
    zero2_kernel<<<dim3(4096), dim3(THREADS), 0, stream>>>(pingA, pingB);

    // ---- head chain: sparse gather-GEMM convs, 2 blocks/CU geometry ----
    gemm_head_kernel<256><<<dim3(640), dim3(512), 0, stream>>>(
        combOut, wpH0, head_b0, actList, pingA, (const _Float16*)zpage);
    {
        const _Float16* s = pingA;
        _Float16* d = pingB;
        for (int i = 0; i < 7; ++i) {
            gemm_head_kernel<512><<<dim3(640), dim3(512), 0, stream>>>(
                s, wpH + (size_t)i * 2359296, head_b + (size_t)i * 512, actList, d,
                (const _Float16*)zpage);
            _Float16* tmp = (_Float16*)s; s = d; d = tmp;
        }
    }

    // ---- predictor (reads pingB), batched ----
    predh_kernel<<<dim3(64, 3, 4), dim3(256), 0, stream>>>(pingB, pred_w, pred_b, (float*)d_out);
}

// Round 16
// 2756.774 us; speedup vs baseline: 1.1017x; 1.1017x over previous
//
#include <hip/hip_runtime.h>
#include <cstdint>
#include <cstddef>

#define THREADS 256

typedef _Float16 f16x8 __attribute__((ext_vector_type(8)));
typedef _Float16 f16x4 __attribute__((ext_vector_type(4)));
typedef _Float16 f16x2 __attribute__((ext_vector_type(2)));
typedef float f32x4 __attribute__((ext_vector_type(4)));
typedef float f32x8 __attribute__((ext_vector_type(8)));

__device__ __forceinline__ void gll16(const void* g, void* l) {
    __builtin_amdgcn_global_load_lds(
        (const __attribute__((address_space(1))) unsigned int*)g,
        (__attribute__((address_space(3))) unsigned int*)l, 16, 0, 0);
}

// ---------------------------------------------------------------------------
// Batched scale weight pack (8 weights, convu format). Slots 1-6 used.
// ---------------------------------------------------------------------------
__global__ void pack_scale_all_kernel(
    const float* __restrict__ w0, const float* __restrict__ w1,
    const float* __restrict__ w2, const float* __restrict__ w3,
    const float* __restrict__ w4, const float* __restrict__ w5,
    const float* __restrict__ w6, const float* __restrict__ w7,
    _Float16* __restrict__ wp)
{
    const int wi = blockIdx.y;
    const float* w = (wi == 0) ? w0 : (wi == 1) ? w1 : (wi == 2) ? w2 : (wi == 3) ? w3
                   : (wi == 4) ? w4 : (wi == 5) ? w5 : (wi == 6) ? w6 : w7;
    const int Cin = (wi == 7) ? 260 : 256;
    const int CC  = (wi == 7) ? 9 : 8;
    _Float16* dst = wp + (size_t)wi * 663552;
    int idx = blockIdx.x * THREADS + threadIdx.x;
    int total = 256 * CC * 4;
    if (idx >= total) return;
    int u = idx & 3;
    int cc = (idx >> 2) % CC;
    int co = (idx >> 2) / CC;
    int ci0 = cc * 32 + u * 8;
    for (int tap = 0; tap < 9; ++tap) {
        f16x8 v;
#pragma unroll
        for (int j = 0; j < 8; ++j) {
            int ci = ci0 + j;
            v[j] = (ci < Cin) ? (_Float16)w[((size_t)co * Cin + ci) * 9 + tap] : (_Float16)0.f;
        }
        *reinterpret_cast<f16x8*>(dst + ((((size_t)tap * CC + cc) * 4 + u) * 256 + co) * 8) = v;
    }
}

// ---------------------------------------------------------------------------
// Dense-GEMM weight pack (Cout=256): [t][co(256)x8kc][8], swizzle kc^(co&7).
// ---------------------------------------------------------------------------
__global__ void pack_wdense_kernel(const float* __restrict__ w, _Float16* __restrict__ wp,
                                   int CinTrue, int CINP)
{
    const int NSTEP = 9 * (CINP / 64);
    int idx = blockIdx.x * THREADS + threadIdx.x;
    if (idx >= 256 * NSTEP * 8) return;
    int kc = idx & 7;
    int t = (idx >> 3) % NSTEP;
    int co = (idx >> 3) / NSTEP;
    int kcs = kc ^ (co & 7);
    int k = t * 64 + kcs * 8;
    int tap = k / CINP;
    int cib = k - tap * CINP;
    f16x8 v;
#pragma unroll
    for (int j = 0; j < 8; ++j) {
        int ci = cib + j;
        v[j] = (ci < CinTrue) ? (_Float16)w[((size_t)co * CinTrue + ci) * 9 + tap] : (_Float16)0.f;
    }
    *reinterpret_cast<f16x8*>(wp + ((size_t)t * 2048 + co * 8 + kc) * 8) = v;
}

// ---------------------------------------------------------------------------
// Batched head-GEMM weight pack (8 layers). Format: [t][gy(4)][r(128)x8kc][8]
// (gy = co quarter). K tap-major, swizzle kc^(r&7) baked.
// ---------------------------------------------------------------------------
__global__ void pack_whead_all_kernel(const float* __restrict__ hw0,
                                      const float* __restrict__ hw,
                                      _Float16* __restrict__ wp0,
                                      _Float16* __restrict__ wpH)
{
    const int wi = blockIdx.y;
    const int Cin = (wi == 0) ? 256 : 512;
    const float* w = (wi == 0) ? hw0 : hw + (size_t)(wi - 1) * 2359296;
    _Float16* wp = (wi == 0) ? wp0 : wpH + (size_t)(wi - 1) * 2359296;
    const int NSTEP = 9 * (Cin / 64);
    int idx = blockIdx.x * THREADS + threadIdx.x;
    int total = 512 * NSTEP * 8;
    if (idx >= total) return;
    int kc = idx & 7;
    int t = (idx >> 3) % NSTEP;
    int co = (idx >> 3) / NSTEP;
    int gy = co >> 7;                  // co quarter (0..3)
    int r = co & 127;
    int kcs = kc ^ (r & 7);
    int k = t * 64 + kcs * 8;
    int tap = k / Cin;
    int cib = k - tap * Cin;
    f16x8 v;
#pragma unroll
    for (int j = 0; j < 8; ++j)
        v[j] = (_Float16)w[((size_t)co * Cin + cib + j) * 9 + tap];
    *reinterpret_cast<f16x8*>(wp + ((size_t)(t * 4 + gy) * 1024 + r * 8 + kc) * 8) = v;
}

__global__ void zerows_kernel(float* __restrict__ p)
{
    p[blockIdx.x * THREADS + threadIdx.x] = 0.f;
}

// Zero pingA and pingB (4x16384x512 f16 each) so inactive rows are exactly 0.
__global__ void zero2_kernel(_Float16* __restrict__ a, _Float16* __restrict__ b)
{
    const size_t N = 4ull * 16384 * 512;
    for (size_t i = ((size_t)blockIdx.x * THREADS + threadIdx.x) * 8; i < N;
         i += (size_t)gridDim.x * THREADS * 8) {
        *reinterpret_cast<f16x8*>(a + i) = (f16x8){};
        *reinterpret_cast<f16x8*>(b + i) = (f16x8){};
    }
}

// ---------------------------------------------------------------------------
// Deterministic active-pixel compaction: fg [4*16384] int -> list[40960] int.
// Consumed in 160 tiles of 256 entries.
// ---------------------------------------------------------------------------
__global__ __launch_bounds__(1024)
void compact_kernel(const int* __restrict__ fg, int* __restrict__ list)
{
    __shared__ int part[1024];
    const int tid = threadIdx.x;
    const int base = tid * 64;
    int cnt = 0;
    for (int j = 0; j < 64; ++j) cnt += (fg[base + j] > 0) ? 1 : 0;
    part[tid] = cnt;
    __syncthreads();
    for (int off = 1; off < 1024; off <<= 1) {
        int v = (tid >= off) ? part[tid - off] : 0;
        __syncthreads();
        part[tid] += v;
        __syncthreads();
    }
    int pos = part[tid] - cnt;
    for (int j = 0; j < 64; ++j)
        if (fg[base + j] > 0) list[pos++] = base + j;
    const int total = part[1023];
    for (int i = total + tid; i < 40960; i += 1024) list[i] = -1;
}

// ---------------------------------------------------------------------------
// Batched NCHW fp32 -> NHWC fp16 transpose, all 4 FPN levels in one launch.
// ---------------------------------------------------------------------------
__global__ __launch_bounds__(256)
void t_all_kernel(const float* __restrict__ s2, const float* __restrict__ s3,
                  const float* __restrict__ s4, const float* __restrict__ s5,
                  _Float16* __restrict__ d2, _Float16* __restrict__ d3,
                  _Float16* __restrict__ d4, _Float16* __restrict__ d5)
{
    __shared__ _Float16 tile[64 * 32];
    const int lvl = blockIdx.z >> 2;
    const int n = blockIdx.z & 3;
    const int HW = 16384 >> (2 * lvl);
    const int p0 = blockIdx.x * 64;
    if (p0 >= HW) return;
    const float* in = (lvl == 0) ? s2 : (lvl == 1) ? s3 : (lvl == 2) ? s4 : s5;
    _Float16* out = (lvl == 0) ? d2 : (lvl == 1) ? d3 : (lvl == 2) ? d4 : d5;
    const int C = 256;
    const int c0 = blockIdx.y * 32;
    const int tid = threadIdx.x;
    {
        int ci = tid >> 3;
        int j8 = (tid & 7) * 8;
        f32x8 v = *reinterpret_cast<const f32x8*>(in + ((size_t)n * C + c0 + ci) * HW + p0 + j8);
#pragma unroll
        for (int j = 0; j < 8; ++j)
            tile[(j8 + j) * 32 + ci] = (_Float16)v[j];
    }
    __syncthreads();
    {
        int px = tid >> 2;
        int u = tid & 3;
        f16x8 v = *reinterpret_cast<const f16x8*>(&tile[px * 32 + u * 8]);
        *reinterpret_cast<f16x8*>(out + ((size_t)n * HW + p0 + px) * C + c0 + u * 8) = v;
    }
}

// ---------------------------------------------------------------------------
// Unified conv -- kept for the small scale convs (64^2/32^2/16^2, slots 1-6).
// ---------------------------------------------------------------------------
template<int INF32, int OUTMODE, int CC>
__global__ __launch_bounds__(512, 4)
void convu_kernel(const void* __restrict__ inv, const _Float16* __restrict__ wp,
                  const float* __restrict__ bias, const int* __restrict__ msk,
                  void* __restrict__ outp, int Cout, int H, int W,
                  int inCst, int outCst, int useMask)
{
    __shared__ _Float16 Xs[2 * 1344 * 8];

    const int tid = threadIdx.x;
    const int lane = tid & 63;
    const int wave = tid >> 6;
    const int lm = lane & 15;
    const int lu = lane >> 4;
    const int waveco = (wave & 1) * 64;
    const int wrow = (wave >> 1) * 4;
    const int n = blockIdx.z;
    const int co0 = blockIdx.y * 128;
    const int tpr = W >> 4;
    const int tx = blockIdx.x % tpr;
    const int ty = blockIdx.x / tpr;
    const int x0 = tx << 4;
    const int y0 = ty << 4;
    const int HW = H * W;

    int soff[3];
#pragma unroll
    for (int t = 0; t < 3; ++t) {
        int s = tid + t * 512;
        int item = s >> 2, u = s & 3;
        int row = item / 18, col = item - row * 18;
        int y = y0 + row - 1, x = x0 + col - 1;
        soff[t] = (s < 1296 && y >= 0 && y < H && x >= 0 && x < W)
                      ? ((n * HW + y * W + x) * inCst + u * 8) : -1;
    }

    f32x4 acc[4][4];
#pragma unroll
    for (int m = 0; m < 4; ++m)
#pragma unroll
        for (int nf = 0; nf < 4; ++nf)
            acc[m][nf] = (f32x4){0.f, 0.f, 0.f, 0.f};

    const size_t tstride = (size_t)CC * 4 * Cout * 8;

    {
        const _Float16* src = (const _Float16*)inv;
#pragma unroll
        for (int t = 0; t < 3; ++t) {
            int s = tid + t * 512;
            if (s < 1296 && soff[t] < 0) {
                *reinterpret_cast<f16x8*>(&Xs[s * 8]) = (f16x8){};
                *reinterpret_cast<f16x8*>(&Xs[(1344 + s) * 8]) = (f16x8){};
            }
        }
#pragma unroll
        for (int t = 0; t < 3; ++t) {
            int s = tid + t * 512;
            if (s < 1296 && soff[t] >= 0)
                gll16(src + soff[t], &Xs[(t * 512 + (tid & ~63)) * 8]);
        }
    }
    __syncthreads();

    int bsel = 0;
    for (int cc = 0; cc < CC; ++cc) {
        if (cc + 1 < CC) {
            const _Float16* src = (const _Float16*)inv;
#pragma unroll
            for (int t = 0; t < 3; ++t) {
                int s = tid + t * 512;
                if (s < 1296 && soff[t] >= 0)
                    gll16(src + soff[t] + (cc + 1) * 32,
                          &Xs[((bsel ^ 1) * 1344 + t * 512 + (tid & ~63)) * 8]);
            }
        }
        {
            const int xbase = bsel * 1344;
            const _Float16* wb = wp + (((size_t)cc * 4 + lu) * Cout + co0 + waveco + lm) * 8;
#pragma unroll
            for (int tap = 0; tap < 9; ++tap) {
                const int dy = tap / 3, dx = tap % 3;
                const _Float16* wt = wb + (size_t)tap * tstride;
                f16x8 a[4], b[4];
#pragma unroll
                for (int m = 0; m < 4; ++m)
                    a[m] = *reinterpret_cast<const f16x8*>(wt + m * 128);
#pragma unroll
                for (int nf = 0; nf < 4; ++nf) {
                    int slot = ((wrow + nf + dy) * 18 + lm + dx) * 4 + lu;
                    b[nf] = *reinterpret_cast<const f16x8*>(&Xs[(xbase + slot) * 8]);
                }
#pragma unroll
                for (int m = 0; m < 4; ++m)
#pragma unroll
                    for (int nf = 0; nf < 4; ++nf)
                        acc[m][nf] = __builtin_amdgcn_mfma_f32_16x16x32_f16(a[m], b[nf], acc[m][nf], 0, 0, 0);
            }
        }
        __syncthreads();
        bsel ^= 1;
    }

    const int xE = x0 + lm;
    const size_t nHW = (size_t)n * HW;
#pragma unroll
    for (int nf = 0; nf < 4; ++nf) {
        const int y = y0 + wrow + nf;
        float mv = 1.f;
        if (useMask) mv = (msk[nHW + y * W + xE] > 0) ? 1.f : 0.f;
        const size_t pixo = (nHW + (size_t)y * W + xE) * outCst;
#pragma unroll
        for (int m = 0; m < 4; ++m) {
            const int cb = co0 + waveco + m * 16 + lu * 4;
            const f32x4 bv = *reinterpret_cast<const f32x4*>(bias + cb);
            if (OUTMODE == 0) {
                f16x4 h;
#pragma unroll
                for (int r = 0; r < 4; ++r)
                    h[r] = (_Float16)(fmaxf(acc[m][nf][r] + bv[r], 0.f) * mv);
                *reinterpret_cast<f16x4*>((_Float16*)outp + pixo + cb) = h;
            } else if (OUTMODE == 1) {
                f32x4 v;
#pragma unroll
                for (int r = 0; r < 4; ++r)
                    v[r] = fmaxf(acc[m][nf][r] + bv[r], 0.f);
                *reinterpret_cast<f32x4*>((float*)outp + pixo + cb) = v;
            } else {
                f32x4 old = *reinterpret_cast<const f32x4*>((float*)outp + pixo + cb);
#pragma unroll
                for (int r = 0; r < 4; ++r)
                    old[r] += fmaxf(acc[m][nf][r] + bv[r], 0.f);
                *reinterpret_cast<f32x4*>((float*)outp + pixo + cb) = old;
            }
        }
    }
}

// ---------------------------------------------------------------------------
// DENSE conv as LDS-staged GEMM tile (p2 + comb @128^2). Unchanged from R14.
// ---------------------------------------------------------------------------
template<int CINP, int MASK>
__global__ __launch_bounds__(512, 1)
void gemm_dense_kernel(const _Float16* __restrict__ in,
                       const _Float16* __restrict__ wpk,
                       const float* __restrict__ bias,
                       const int* __restrict__ fg,
                       _Float16* __restrict__ outp, int outCst,
                       const _Float16* __restrict__ zpage)
{
    constexpr int SPT = CINP / 64;
    __shared__ __attribute__((aligned(16))) char ldsb[2 * 65536];  // 128 KB

    const int job = blockIdx.x;        // 0..255
    const int xcd = job & 7;
    const int idx = job >> 3;          // 0..31
    const int img = idx >> 3;          // 0..3
    const int tile = xcd * 8 + (idx & 7);
    const int x0 = (tile & 7) << 4;
    const int y0 = (tile >> 3) << 4;

    const int tid = threadIdx.x;
    const int lane = tid & 63;
    const int wave = tid >> 6;
    const int lm = lane & 15;
    const int lu = lane >> 4;
    const int wco = (wave & 1) * 128;
    const int wpx = (wave >> 1) * 64;

    const _Float16* bsrc = in + (size_t)img * 16384 * CINP;

    const _Float16* bptr[4];
    unsigned long long inbm = 0;
    int dstA[4], dstB[4];
#pragma unroll
    for (int s = 0; s < 4; ++s) {
        const int row = s * 64 + (tid >> 3);   // 0..255
        const int kc = (tid & 7) ^ (row & 7);
        const int y = y0 + (row >> 4);
        const int x = x0 + (row & 15);
        bptr[s] = bsrc + (size_t)(y * 128 + x) * CINP + kc * 8;
#pragma unroll
        for (int tap = 0; tap < 9; ++tap) {
            const int yy = y + tap / 3 - 1;
            const int xx = x + tap % 3 - 1;
            if ((unsigned)yy < 128u && (unsigned)xx < 128u)
                inbm |= 1ull << (s * 9 + tap);
        }
        dstA[s] = (s * 512 + (tid & ~63)) * 16;
        dstB[s] = 32768 + (s * 512 + (tid & ~63)) * 16;
    }

    auto STAGE = [&](int t, int bufByte) {
        const _Float16* as = wpk + (size_t)t * 16384;
#pragma unroll
        for (int s = 0; s < 4; ++s)
            gll16(as + (size_t)(s * 512 + tid) * 8, ldsb + bufByte + dstA[s]);
        const int tap = t / SPT;
        const int ci0 = (t % SPT) * 64;
        const int delta = ((tap / 3 - 1) * 128 + (tap % 3 - 1)) * CINP + ci0;
#pragma unroll
        for (int s = 0; s < 4; ++s) {
            const bool ok = (inbm >> (s * 9 + tap)) & 1ull;
            const _Float16* src = ok ? (bptr[s] + delta) : zpage;
            gll16(src, ldsb + bufByte + dstB[s]);
        }
    };

    f32x4 acc[8][4];
#pragma unroll
    for (int m = 0; m < 8; ++m)
#pragma unroll
        for (int n = 0; n < 4; ++n)
            acc[m][n] = (f32x4){0.f, 0.f, 0.f, 0.f};

    STAGE(0, 0);
    __syncthreads();

    int bsel = 0;
    for (int cb = 0; cb < SPT; ++cb) {
        for (int tap = 0; tap < 9; ++tap) {
            if (tap < 8) STAGE((tap + 1) * SPT + cb, (bsel ^ 1) * 65536);
            else if (cb + 1 < SPT) STAGE(cb + 1, (bsel ^ 1) * 65536);
            const int ab = bsel * 65536;
#pragma unroll
            for (int s = 0; s < 2; ++s) {
                f16x8 bfr[4];
#pragma unroll
                for (int n = 0; n < 4; ++n) {
                    const int row = wpx + n * 16 + lm;
                    const int ch = (s * 4 + lu) ^ (row & 7);
                    bfr[n] = *reinterpret_cast<const f16x8*>(ldsb + ab + 32768 + row * 128 + ch * 16);
                }
#pragma unroll
                for (int m = 0; m < 8; ++m) {
                    const int row = wco + m * 16 + lm;
                    const int ch = (s * 4 + lu) ^ (row & 7);
                    const f16x8 afr = *reinterpret_cast<const f16x8*>(ldsb + ab + row * 128 + ch * 16);
#pragma unroll
                    for (int n = 0; n < 4; ++n)
                        acc[m][n] = __builtin_amdgcn_mfma_f32_16x16x32_f16(afr, bfr[n], acc[m][n], 0, 0, 0);
                }
            }
            __syncthreads();
            bsel ^= 1;
        }
    }

    const int base = img * 16384;
#pragma unroll
    for (int n = 0; n < 4; ++n) {
        const int px = wpx + n * 16 + lm;
        const int y = y0 + (px >> 4), x = x0 + (px & 15);
        float mv = 1.f;
        if (MASK) mv = (fg[base + y * 128 + x] > 0) ? 1.f : 0.f;
        _Float16* pp = outp + ((size_t)base + y * 128 + x) * outCst + wco;
#pragma unroll
        for (int m = 0; m < 8; ++m) {
            const f32x4 bv = *reinterpret_cast<const f32x4*>(bias + wco + m * 16 + lu * 4);
            f16x4 h;
#pragma unroll
            for (int rr = 0; rr < 4; ++rr)
                h[rr] = (_Float16)(fmaxf(acc[m][n][rr] + bv[rr], 0.f) * mv);
            *reinterpret_cast<f16x4*>(pp + m * 16 + lu * 4) = h;
        }
    }
}

// ---------------------------------------------------------------------------
// SPARSE head conv as gather-GEMM. R16: same 128co x 256px / 48KB single-buf
// geometry as R15, but NO launch-bounds VGPR cap -- R9/R15 both showed
// __launch_bounds__(512,4) forces VGPR=64 and spills acc to scratch
// (WRITE_SIZE 115MB, MfmaUtil 22%). Co-residency is LDS-driven anyway:
// 48KB -> 3 blocks/CU; natural VGPR ~100 < 256 allows 8 waves/SIMD.
// ---------------------------------------------------------------------------
template<int CIN>
__global__ __launch_bounds__(512)
void gemm_head_kernel(const _Float16* __restrict__ in,
                      const _Float16* __restrict__ wpk,
                      const float* __restrict__ bias,
                      const int* __restrict__ list,
                      _Float16* __restrict__ outp,
                      const _Float16* __restrict__ zpage)
{
    constexpr int SPT = CIN / 64;
    __shared__ __attribute__((aligned(16))) char ldsb[49152];  // 48 KB: A 16K + B 32K

    const int job = blockIdx.x;        // 0..639
    const int xcd = job & 7;
    const int r8 = job >> 3;           // 0..79
    const int tile = xcd * 20 + (r8 >> 2);   // 160 tiles, 20 per XCD
    const int gy = r8 & 3;                   // co quarter
    if (list[tile * 256] < 0) return;        // empty tile

    const int tid = threadIdx.x;
    const int lane = tid & 63;
    const int wave = tid >> 6;
    const int lm = lane & 15;
    const int lu = lane >> 4;
    const int wco = (wave & 1) * 64;
    const int g64 = (wave >> 1) * 64;
    const int co0 = gy * 128;

    // ---- per-thread staging state: 4 B row-slots, 2 A slots ----
    const _Float16* bptr[4];
    unsigned long long inbm = 0;
#pragma unroll
    for (int s = 0; s < 4; ++s) {
        const int row = s * 64 + (tid >> 3);          // 0..255
        const int kc = (tid & 7) ^ (row & 7);
        const int entry = list[tile * 256 + row];
        bptr[s] = zpage;
        if (entry >= 0) {
            const int y = (entry >> 7) & 127;
            const int x = entry & 127;
            bptr[s] = in + (size_t)entry * CIN + kc * 8;
#pragma unroll
            for (int tap = 0; tap < 9; ++tap) {
                const int yy = y + tap / 3 - 1;
                const int xx = x + tap % 3 - 1;
                if ((unsigned)yy < 128u && (unsigned)xx < 128u)
                    inbm |= 1ull << (s * 9 + tap);
            }
        }
    }
    const int ldst = (tid & ~63) * 16;   // wave-uniform LDS base component

    auto STAGE = [&](int t) {
        const _Float16* as = wpk + (size_t)(t * 4 + gy) * 8192;
        gll16(as + (size_t)tid * 8, ldsb + ldst);
        gll16(as + (size_t)(512 + tid) * 8, ldsb + 8192 + ldst);
        const int tap = t / SPT;
        const int ci0 = (t % SPT) * 64;
        const int delta = ((tap / 3 - 1) * 128 + (tap % 3 - 1)) * CIN + ci0;
#pragma unroll
        for (int s = 0; s < 4; ++s) {
            const bool ok = (inbm >> (s * 9 + tap)) & 1ull;
            const _Float16* src = ok ? (bptr[s] + delta) : zpage;
            gll16(src, ldsb + 16384 + s * 8192 + ldst);
        }
    };

    f32x4 acc[4][4];
#pragma unroll
    for (int m = 0; m < 4; ++m)
#pragma unroll
        for (int n = 0; n < 4; ++n)
            acc[m][n] = (f32x4){0.f, 0.f, 0.f, 0.f};

    for (int cb = 0; cb < SPT; ++cb) {
        for (int tap = 0; tap < 9; ++tap) {
            STAGE(tap * SPT + cb);
            __syncthreads();   // drains this block's loads (vmcnt0 at barrier)
#pragma unroll
            for (int s = 0; s < 2; ++s) {
                f16x8 bfr[4];
#pragma unroll
                for (int n = 0; n < 4; ++n) {
                    const int row = g64 + n * 16 + lm;
                    const int ch = (s * 4 + lu) ^ (row & 7);
                    bfr[n] = *reinterpret_cast<const f16x8*>(ldsb + 16384 + row * 128 + ch * 16);
                }
#pragma unroll
                for (int m = 0; m < 4; ++m) {
                    const int row = wco + m * 16 + lm;
                    const int ch = (s * 4 + lu) ^ (row & 7);
                    const f16x8 afr = *reinterpret_cast<const f16x8*>(ldsb + row * 128 + ch * 16);
#pragma unroll
                    for (int n = 0; n < 4; ++n)
                        acc[m][n] = __builtin_amdgcn_mfma_f32_16x16x32_f16(afr, bfr[n], acc[m][n], 0, 0, 0);
                }
            }
            __syncthreads();   // all reads done before next STAGE overwrites
        }
    }

    // ---- epilogue: scatter active rows, bias+relu ----
#pragma unroll
    for (int n = 0; n < 4; ++n) {
        const int entry = list[tile * 256 + g64 + n * 16 + lm];
        if (entry < 0) continue;
        _Float16* pp = outp + (size_t)entry * 512 + co0 + wco;
#pragma unroll
        for (int m = 0; m < 4; ++m) {
            const f32x4 bv = *reinterpret_cast<const f32x4*>(bias + co0 + wco + m * 16 + lu * 4);
            f16x4 h;
#pragma unroll
            for (int rr = 0; rr < 4; ++rr)
                h[rr] = (_Float16)fmaxf(acc[m][n][rr] + bv[rr], 0.f);
            *reinterpret_cast<f16x4*>(pp + m * 16 + lu * 4) = h;
        }
    }
}

// ---------------------------------------------------------------------------
// fp16 NHWC 2x bilinear upsample (align_corners=False -> clamped 0.75/0.25).
// ---------------------------------------------------------------------------
__global__ void up2h_kernel(const _Float16* __restrict__ in, _Float16* __restrict__ out,
                            int Hin, int Win)
{
    const int Wout = Win << 1, Hout = Hin << 1;
    const int lw = __ffs(Wout) - 1, lh = __ffs(Hout) - 1;
    int i = blockIdx.x * THREADS + threadIdx.x;
    if (i >= 4 * Hout * Wout * 32) return;
    int u = i & 31;
    int p = i >> 5;
    int x = p & (Wout - 1);
    int y = (p >> lw) & (Hout - 1);
    int n = p >> (lw + lh);
    int iy = y >> 1, ix = x >> 1;
    int y2 = (y & 1) ? min(iy + 1, Hin - 1) : max(iy - 1, 0);
    int x2 = (x & 1) ? min(ix + 1, Win - 1) : max(ix - 1, 0);
    const _Float16* base = in + ((size_t)n * Hin * Win) * 256 + u * 8;
    f16x8 v00 = *reinterpret_cast<const f16x8*>(base + (iy * Win + ix) * 256);
    f16x8 v01 = *reinterpret_cast<const f16x8*>(base + (iy * Win + x2) * 256);
    f16x8 v10 = *reinterpret_cast<const f16x8*>(base + (y2 * Win + ix) * 256);
    f16x8 v11 = *reinterpret_cast<const f16x8*>(base + (y2 * Win + x2) * 256);
    f16x8 o;
#pragma unroll
    for (int j = 0; j < 8; ++j) {
        float v = 0.5625f * (float)v00[j] + 0.1875f * ((float)v01[j] + (float)v10[j])
                + 0.0625f * (float)v11[j];
        o[j] = (_Float16)v;
    }
    *reinterpret_cast<f16x8*>(out + (((size_t)n * Hout * Wout) + y * Wout + x) * 256 + u * 8) = o;
}

// fp32 NHWC 64^2 t64sum -> 128^2 upsample-ADD into fp16 Xch (stride 320, ch 0..255).
__global__ void up2addh_kernel(const float* __restrict__ in, _Float16* __restrict__ Xch)
{
    int i = blockIdx.x * THREADS + threadIdx.x;
    if (i >= 4 * 16384 * 32) return;
    int u = i & 31;
    int p = i >> 5;
    int x = p & 127;
    int y = (p >> 7) & 127;
    int n = p >> 14;
    int iy = y >> 1, ix = x >> 1;
    int y2 = (y & 1) ? min(iy + 1, 63) : max(iy - 1, 0);
    int x2 = (x & 1) ? min(ix + 1, 63) : max(ix - 1, 0);
    const float* base = in + ((size_t)n * 4096) * 256 + u * 8;
    f32x8 v00 = *reinterpret_cast<const f32x8*>(base + (iy * 64 + ix) * 256);
    f32x8 v01 = *reinterpret_cast<const f32x8*>(base + (iy * 64 + x2) * 256);
    f32x8 v10 = *reinterpret_cast<const f32x8*>(base + (y2 * 64 + ix) * 256);
    f32x8 v11 = *reinterpret_cast<const f32x8*>(base + (y2 * 64 + x2) * 256);
    _Float16* dst = Xch + ((size_t)n * 16384 + y * 128 + x) * 320 + u * 8;
    f16x8 d = *reinterpret_cast<const f16x8*>(dst);
#pragma unroll
    for (int j = 0; j < 8; ++j)
        d[j] = (_Float16)((float)d[j] + 0.5625f * v00[j]
               + 0.1875f * (v01[j] + v10[j]) + 0.0625f * v11[j]);
    *reinterpret_cast<f16x8*>(dst) = d;
}

// Coords into fp16 Xch (stride 320) channels 256..259; zero channels 260..319.
__global__ void coords2h_kernel(const float* __restrict__ rel, const float* __restrict__ abs_,
                                _Float16* __restrict__ Xch)
{
    int i = blockIdx.x * THREADS + threadIdx.x;
    if (i >= 4 * 16384) return;
    int px = i & 16383;
    int n = i >> 14;
    _Float16* dst = Xch + ((size_t)n * 16384 + px) * 320 + 256;
    f16x8 v0 = (f16x8){};
    v0[0] = (_Float16)rel[((size_t)n * 2 + 0) * 16384 + px];
    v0[1] = (_Float16)rel[((size_t)n * 2 + 1) * 16384 + px];
    v0[2] = (_Float16)abs_[((size_t)n * 2 + 0) * 16384 + px];
    v0[3] = (_Float16)abs_[((size_t)n * 2 + 1) * 16384 + px];
    *reinterpret_cast<f16x8*>(dst) = v0;
#pragma unroll
    for (int b = 1; b < 8; ++b)
        *reinterpret_cast<f16x8*>(dst + b * 8) = (f16x8){};
}

// 1x1 predictor: NHWC fp16 [n][16384][512] -> NCHW fp32 [n][75][16384].
__global__ __launch_bounds__(256)
void predh_kernel(const _Float16* __restrict__ in, const float* __restrict__ w,
                  const float* __restrict__ bias, float* __restrict__ out)
{
    __shared__ _Float16 lw[25 * 512];
    const int co0 = blockIdx.y * 25;
    const int n = blockIdx.z;
    for (int idx = threadIdx.x; idx < 25 * 512; idx += 256)
        lw[idx] = (_Float16)w[(size_t)(co0 + idx / 512) * 512 + (idx & 511)];
    __syncthreads();
    int px = blockIdx.x * 256 + threadIdx.x;
    const _Float16* ip = in + ((size_t)n * 16384 + px) * 512;
    float acc[25];
#pragma unroll
    for (int j = 0; j < 25; ++j) acc[j] = bias[co0 + j];
    for (int g = 0; g < 64; ++g) {
        union { f16x8 v; f16x2 p[4]; } xv;
        xv.v = *reinterpret_cast<const f16x8*>(ip + g * 8);
#pragma unroll
        for (int j = 0; j < 25; ++j) {
            union { f16x8 v; f16x2 p[4]; } wv;
            wv.v = *reinterpret_cast<const f16x8*>(&lw[j * 512 + g * 8]);
#if __has_builtin(__builtin_amdgcn_fdot2)
#pragma unroll
            for (int k = 0; k < 4; ++k)
                acc[j] = __builtin_amdgcn_fdot2(xv.p[k], wv.p[k], acc[j], false);
#else
#pragma unroll
            for (int k = 0; k < 8; ++k)
                acc[j] = fmaf((float)xv.v[k], (float)wv.v[k], acc[j]);
#endif
        }
    }
    float* op = out + ((size_t)n * 75) * 16384 + px;
#pragma unroll
    for (int j = 0; j < 25; ++j)
        op[(size_t)(co0 + j) * 16384] = acc[j];
}

extern "C" void kernel_launch(void* const* d_in, const int* in_sizes, int n_in,
                              void* d_out, int out_size, void* d_ws, size_t ws_size,
                              hipStream_t stream)
{
    const float* p2   = (const float*)d_in[0];
    const float* p3   = (const float*)d_in[1];
    const float* p4   = (const float*)d_in[2];
    const float* p5   = (const float*)d_in[3];
    const float* rel  = (const float*)d_in[4];
    const float* abs_ = (const float*)d_in[5];
    const int*   fg   = (const int*)d_in[6];
    const float* w_p2_0 = (const float*)d_in[7];
    const float* b_p2_0 = (const float*)d_in[8];
    const float* w_p3_0 = (const float*)d_in[9];
    const float* b_p3_0 = (const float*)d_in[10];
    const float* w_p4_0 = (const float*)d_in[11];
    const float* b_p4_0 = (const float*)d_in[12];
    const float* w_p4_1 = (const float*)d_in[13];
    const float* b_p4_1 = (const float*)d_in[14];
    const float* w_p5_0 = (const float*)d_in[15];
    const float* b_p5_0 = (const float*)d_in[16];
    const float* w_p5_1 = (const float*)d_in[17];
    const float* b_p5_1 = (const float*)d_in[18];
    const float* w_p5_2 = (const float*)d_in[19];
    const float* b_p5_2 = (const float*)d_in[20];
    const float* comb_w = (const float*)d_in[21];
    const float* comb_b = (const float*)d_in[22];
    const float* head_w0 = (const float*)d_in[23];
    const float* head_b0 = (const float*)d_in[24];
    const float* head_w  = (const float*)d_in[25];
    const float* head_b  = (const float*)d_in[26];
    const float* pred_w  = (const float*)d_in[27];
    const float* pred_b  = (const float*)d_in[28];

    // Workspace layout (float offsets). Total 58,704,896 floats = 234.8 MB.
    float* ws = (float*)d_ws;
    _Float16* Xch     = (_Float16*)ws;                       // 10,485,760 fl as f16 (stride 320)
    _Float16* pingA   = (_Float16*)ws;                       // aliases Xch (dead after comb)
    _Float16* pingB   = (_Float16*)(ws + 18874368);          // 16,777,216 fl
    float*    regD    = ws + 35651584;                       //  8,388,608 fl
    _Float16* p2h     = (_Float16*)regD;
    _Float16* combOut = (_Float16*)regD;
    float*    t64sum  = regD;
    _Float16* t64b    = (_Float16*)(regD + 4194304);
    _Float16* t64c    = (_Float16*)(regD + 5242880);
    _Float16* t32a    = (_Float16*)(regD + 6291456);
    _Float16* t32b    = (_Float16*)(regD + 6553600);
    _Float16* t32c    = (_Float16*)(regD + 6815744);
    _Float16* t16a    = (_Float16*)(regD + 7077888);
    _Float16* p3h     = (_Float16*)(ws + 44040192);          //  2,097,152 fl
    _Float16* p4h     = (_Float16*)(ws + 46137344);          //    524,288 fl
    _Float16* p5h     = (_Float16*)(ws + 46661632);          //    131,072 fl
    _Float16* wpScale = (_Float16*)(ws + 46792704);          //  2,654,208 fl (8 x 663,552 f16)
    float*    zpage   = ws + 49446912;                       //      1,024 fl (4 KB zeros)
    _Float16* wpH0    = (_Float16*)(ws + 49447936);          //    589,824 fl (1,179,648 f16)
    _Float16* wpH     = (_Float16*)(ws + 50037760);          //  8,257,536 fl (7 x 2,359,296 f16)
    int*      actList = (int*)(ws + 58295296);               //     40,960 ints
    _Float16* wpComb  = (_Float16*)(ws + 58336256);          //    368,640 fl (737,280 f16)
    _Float16* wpDp2   = wpScale;                             // dense p2 pack reuses slot 0

    auto wpS = [&](int i) { return wpScale + (size_t)i * 663552; };

    auto convu = [&](const void* in, const _Float16* wpk, const float* bs, void* outp,
                     int mode, int Cout, int H, int W,
                     int inCst, int outCst) {
        dim3 grid((W / 16) * (H / 16), Cout / 128, 4);
        dim3 blk(512);
        if (mode == 0)
            convu_kernel<0, 0, 8><<<grid, blk, 0, stream>>>(in, wpk, bs, fg, outp, Cout, H, W, inCst, outCst, 0);
        else if (mode == 1)
            convu_kernel<0, 1, 8><<<grid, blk, 0, stream>>>(in, wpk, bs, fg, outp, Cout, H, W, inCst, outCst, 0);
        else
            convu_kernel<0, 2, 8><<<grid, blk, 0, stream>>>(in, wpk, bs, fg, outp, Cout, H, W, inCst, outCst, 0);
    };
    auto up2h = [&](const _Float16* in, _Float16* out, int Hin, int Win) {
        int total = 4 * (Hin * 2) * (Win * 2) * 32;
        up2h_kernel<<<dim3((total + THREADS - 1) / THREADS), dim3(THREADS), 0, stream>>>(
            in, out, Hin, Win);
    };

    // ---- batched packs + zero-page + compaction + batched transposes ----
    zerows_kernel<<<dim3(4), dim3(THREADS), 0, stream>>>(zpage);
    compact_kernel<<<dim3(1), dim3(1024), 0, stream>>>(fg, actList);
    pack_scale_all_kernel<<<dim3(36, 8), dim3(THREADS), 0, stream>>>(
        w_p2_0, w_p3_0, w_p4_0, w_p4_1, w_p5_0, w_p5_1, w_p5_2, comb_w, wpScale);
    pack_wdense_kernel<<<dim3(288), dim3(THREADS), 0, stream>>>(w_p2_0, wpDp2, 256, 256);
    pack_wdense_kernel<<<dim3(360), dim3(THREADS), 0, stream>>>(comb_w, wpComb, 260, 320);
    pack_whead_all_kernel<<<dim3(1152, 8), dim3(THREADS), 0, stream>>>(
        head_w0, head_w, wpH0, wpH);
    t_all_kernel<<<dim3(256, 8, 16), dim3(256), 0, stream>>>(
        p2, p3, p4, p5, p2h, p3h, p4h, p5h);

    // ---- p2 scale head -> Xch (fp16 NHWC-320, dense GEMM tile), coords ----
    gemm_dense_kernel<256, 0><<<dim3(256), dim3(512), 0, stream>>>(
        p2h, wpDp2, b_p2_0, fg, Xch, 320, (const _Float16*)zpage);
    coords2h_kernel<<<dim3(256), dim3(THREADS), 0, stream>>>(rel, abs_, Xch);

    // ---- p3 -> t64sum (fp32 write) ----
    convu(p3h, wpS(1), b_p3_0, t64sum, 1, 256, 64, 64, 256, 256);

    // ---- p4 chain: conv32 -> up -> conv64 (fp32 add into t64sum) ----
    convu(p4h, wpS(2), b_p4_0, t32a, 0, 256, 32, 32, 256, 256);
    up2h(t32a, t64b, 32, 32);
    convu(t64b, wpS(3), b_p4_1, t64sum, 2, 256, 64, 64, 256, 256);

    // ---- p5 chain: conv16 -> up -> conv32 -> up -> conv64 (fp32 add) ----
    convu(p5h, wpS(4), b_p5_0, t16a, 0, 256, 16, 16, 256, 256);
    up2h(t16a, t32b, 16, 16);
    convu(t32b, wpS(5), b_p5_1, t32c, 0, 256, 32, 32, 256, 256);
    up2h(t32c, t64c, 32, 32);
    convu(t64c, wpS(6), b_p5_2, t64sum, 2, 256, 64, 64, 256, 256);

    // ---- single upsample-add of merged 64^2 sum into fp16 Xch (stride 320) ----
    up2addh_kernel<<<dim3(8192), dim3(THREADS), 0, stream>>>(t64sum, Xch);

    // ---- comb conv (Xch fp16 NHWC-320 -> combOut fp16 NHWC-256), dense GEMM ----
    gemm_dense_kernel<320, 1><<<dim3(256), dim3(512), 0, stream>>>(
        Xch, wpComb, comb_b, fg, combOut, 256, (const _Float16*)zpage);

    // ---- zero ping buffers (Xch dead now; inactive rows must be exactly 0) ----
    zero2_kernel<<<dim3(4096), dim3(THREADS), 0, stream>>>(pingA, pingB);

    // ---- head chain: sparse gather-GEMM convs, LDS-driven 3 blocks/CU ----
    gemm_head_kernel<256><<<dim3(640), dim3(512), 0, stream>>>(
        combOut, wpH0, head_b0, actList, pingA, (const _Float16*)zpage);
    {
        const _Float16* s = pingA;
        _Float16* d = pingB;
        for (int i = 0; i < 7; ++i) {
            gemm_head_kernel<512><<<dim3(640), dim3(512), 0, stream>>>(
                s, wpH + (size_t)i * 2359296, head_b + (size_t)i * 512, actList, d,
                (const _Float16*)zpage);
            _Float16* tmp = (_Float16*)s; s = d; d = tmp;
        }
    }

    // ---- predictor (reads pingB), batched ----
    predh_kernel<<<dim3(64, 3, 4), dim3(256), 0, stream>>>(pingB, pred_w, pred_b, (float*)d_out);
}

// Round 17
// 2165.736 us; speedup vs baseline: 1.4024x; 1.2729x over previous
//
#include <hip/hip_runtime.h>
#include <cstdint>
#include <cstddef>

#define THREADS 256

typedef _Float16 f16x8 __attribute__((ext_vector_type(8)));
typedef _Float16 f16x4 __attribute__((ext_vector_type(4)));
typedef _Float16 f16x2 __attribute__((ext_vector_type(2)));
typedef float f32x4 __attribute__((ext_vector_type(4)));
typedef float f32x8 __attribute__((ext_vector_type(8)));

__device__ __forceinline__ void gll16(const void* g, void* l) {
    __builtin_amdgcn_global_load_lds(
        (const __attribute__((address_space(1))) unsigned int*)g,
        (__attribute__((address_space(3))) unsigned int*)l, 16, 0, 0);
}

// ---------------------------------------------------------------------------
// Batched scale weight pack (8 weights, convu format). Slots 1-6 used.
// ---------------------------------------------------------------------------
__global__ void pack_scale_all_kernel(
    const float* __restrict__ w0, const float* __restrict__ w1,
    const float* __restrict__ w2, const float* __restrict__ w3,
    const float* __restrict__ w4, const float* __restrict__ w5,
    const float* __restrict__ w6, const float* __restrict__ w7,
    _Float16* __restrict__ wp)
{
    const int wi = blockIdx.y;
    const float* w = (wi == 0) ? w0 : (wi == 1) ? w1 : (wi == 2) ? w2 : (wi == 3) ? w3
                   : (wi == 4) ? w4 : (wi == 5) ? w5 : (wi == 6) ? w6 : w7;
    const int Cin = (wi == 7) ? 260 : 256;
    const int CC  = (wi == 7) ? 9 : 8;
    _Float16* dst = wp + (size_t)wi * 663552;
    int idx = blockIdx.x * THREADS + threadIdx.x;
    int total = 256 * CC * 4;
    if (idx >= total) return;
    int u = idx & 3;
    int cc = (idx >> 2) % CC;
    int co = (idx >> 2) / CC;
    int ci0 = cc * 32 + u * 8;
    for (int tap = 0; tap < 9; ++tap) {
        f16x8 v;
#pragma unroll
        for (int j = 0; j < 8; ++j) {
            int ci = ci0 + j;
            v[j] = (ci < Cin) ? (_Float16)w[((size_t)co * Cin + ci) * 9 + tap] : (_Float16)0.f;
        }
        *reinterpret_cast<f16x8*>(dst + ((((size_t)tap * CC + cc) * 4 + u) * 256 + co) * 8) = v;
    }
}

// ---------------------------------------------------------------------------
// Dense-GEMM weight pack (Cout=256): [t][co(256)x8kc][8], swizzle kc^(co&7).
// ---------------------------------------------------------------------------
__global__ void pack_wdense_kernel(const float* __restrict__ w, _Float16* __restrict__ wp,
                                   int CinTrue, int CINP)
{
    const int NSTEP = 9 * (CINP / 64);
    int idx = blockIdx.x * THREADS + threadIdx.x;
    if (idx >= 256 * NSTEP * 8) return;
    int kc = idx & 7;
    int t = (idx >> 3) % NSTEP;
    int co = (idx >> 3) / NSTEP;
    int kcs = kc ^ (co & 7);
    int k = t * 64 + kcs * 8;
    int tap = k / CINP;
    int cib = k - tap * CINP;
    f16x8 v;
#pragma unroll
    for (int j = 0; j < 8; ++j) {
        int ci = cib + j;
        v[j] = (ci < CinTrue) ? (_Float16)w[((size_t)co * CinTrue + ci) * 9 + tap] : (_Float16)0.f;
    }
    *reinterpret_cast<f16x8*>(wp + ((size_t)t * 2048 + co * 8 + kc) * 8) = v;
}

// ---------------------------------------------------------------------------
// Batched head-GEMM weight pack (8 layers). R14 format: [t][gy(2)][r(256)x8kc][8]
// (gy = co half). K tap-major, swizzle kc^(r&7) baked.
// ---------------------------------------------------------------------------
__global__ void pack_whead_all_kernel(const float* __restrict__ hw0,
                                      const float* __restrict__ hw,
                                      _Float16* __restrict__ wp0,
                                      _Float16* __restrict__ wpH)
{
    const int wi = blockIdx.y;
    const int Cin = (wi == 0) ? 256 : 512;
    const float* w = (wi == 0) ? hw0 : hw + (size_t)(wi - 1) * 2359296;
    _Float16* wp = (wi == 0) ? wp0 : wpH + (size_t)(wi - 1) * 2359296;
    const int NSTEP = 9 * (Cin / 64);
    int idx = blockIdx.x * THREADS + threadIdx.x;
    int total = 512 * NSTEP * 8;
    if (idx >= total) return;
    int kc = idx & 7;
    int t = (idx >> 3) % NSTEP;
    int co = (idx >> 3) / NSTEP;
    int gy = co >> 8;
    int r = co & 255;
    int kcs = kc ^ (r & 7);
    int k = t * 64 + kcs * 8;
    int tap = k / Cin;
    int cib = k - tap * Cin;
    f16x8 v;
#pragma unroll
    for (int j = 0; j < 8; ++j)
        v[j] = (_Float16)w[((size_t)co * Cin + cib + j) * 9 + tap];
    *reinterpret_cast<f16x8*>(wp + ((size_t)(t * 2 + gy) * 2048 + r * 8 + kc) * 8) = v;
}

__global__ void zerows_kernel(float* __restrict__ p)
{
    p[blockIdx.x * THREADS + threadIdx.x] = 0.f;
}

// Zero pingA and pingB (4x16384x512 f16 each) so inactive rows are exactly 0.
__global__ void zero2_kernel(_Float16* __restrict__ a, _Float16* __restrict__ b)
{
    const size_t N = 4ull * 16384 * 512;
    for (size_t i = ((size_t)blockIdx.x * THREADS + threadIdx.x) * 8; i < N;
         i += (size_t)gridDim.x * THREADS * 8) {
        *reinterpret_cast<f16x8*>(a + i) = (f16x8){};
        *reinterpret_cast<f16x8*>(b + i) = (f16x8){};
    }
}

// ---------------------------------------------------------------------------
// Deterministic active-pixel compaction: fg [4*16384] int -> list[40960] int
// (entries img*16384+pix in scan order; padded with -1). One 1024-thr block.
// Consumed in 128 tiles of 320 entries.
// ---------------------------------------------------------------------------
__global__ __launch_bounds__(1024)
void compact_kernel(const int* __restrict__ fg, int* __restrict__ list)
{
    __shared__ int part[1024];
    const int tid = threadIdx.x;
    const int base = tid * 64;
    int cnt = 0;
    for (int j = 0; j < 64; ++j) cnt += (fg[base + j] > 0) ? 1 : 0;
    part[tid] = cnt;
    __syncthreads();
    for (int off = 1; off < 1024; off <<= 1) {
        int v = (tid >= off) ? part[tid - off] : 0;
        __syncthreads();
        part[tid] += v;
        __syncthreads();
    }
    int pos = part[tid] - cnt;
    for (int j = 0; j < 64; ++j)
        if (fg[base + j] > 0) list[pos++] = base + j;
    const int total = part[1023];
    for (int i = total + tid; i < 40960; i += 1024) list[i] = -1;
}

// ---------------------------------------------------------------------------
// Batched NCHW fp32 -> NHWC fp16 transpose, all 4 FPN levels in one launch.
// ---------------------------------------------------------------------------
__global__ __launch_bounds__(256)
void t_all_kernel(const float* __restrict__ s2, const float* __restrict__ s3,
                  const float* __restrict__ s4, const float* __restrict__ s5,
                  _Float16* __restrict__ d2, _Float16* __restrict__ d3,
                  _Float16* __restrict__ d4, _Float16* __restrict__ d5)
{
    __shared__ _Float16 tile[64 * 32];
    const int lvl = blockIdx.z >> 2;
    const int n = blockIdx.z & 3;
    const int HW = 16384 >> (2 * lvl);
    const int p0 = blockIdx.x * 64;
    if (p0 >= HW) return;
    const float* in = (lvl == 0) ? s2 : (lvl == 1) ? s3 : (lvl == 2) ? s4 : s5;
    _Float16* out = (lvl == 0) ? d2 : (lvl == 1) ? d3 : (lvl == 2) ? d4 : d5;
    const int C = 256;
    const int c0 = blockIdx.y * 32;
    const int tid = threadIdx.x;
    {
        int ci = tid >> 3;
        int j8 = (tid & 7) * 8;
        f32x8 v = *reinterpret_cast<const f32x8*>(in + ((size_t)n * C + c0 + ci) * HW + p0 + j8);
#pragma unroll
        for (int j = 0; j < 8; ++j)
            tile[(j8 + j) * 32 + ci] = (_Float16)v[j];
    }
    __syncthreads();
    {
        int px = tid >> 2;
        int u = tid & 3;
        f16x8 v = *reinterpret_cast<const f16x8*>(&tile[px * 32 + u * 8]);
        *reinterpret_cast<f16x8*>(out + ((size_t)n * HW + p0 + px) * C + c0 + u * 8) = v;
    }
}

// ---------------------------------------------------------------------------
// Unified conv -- kept for the small scale convs (64^2/32^2/16^2, slots 1-6).
// ---------------------------------------------------------------------------
template<int INF32, int OUTMODE, int CC>
__global__ __launch_bounds__(512, 4)
void convu_kernel(const void* __restrict__ inv, const _Float16* __restrict__ wp,
                  const float* __restrict__ bias, const int* __restrict__ msk,
                  void* __restrict__ outp, int Cout, int H, int W,
                  int inCst, int outCst, int useMask)
{
    __shared__ _Float16 Xs[2 * 1344 * 8];

    const int tid = threadIdx.x;
    const int lane = tid & 63;
    const int wave = tid >> 6;
    const int lm = lane & 15;
    const int lu = lane >> 4;
    const int waveco = (wave & 1) * 64;
    const int wrow = (wave >> 1) * 4;
    const int n = blockIdx.z;
    const int co0 = blockIdx.y * 128;
    const int tpr = W >> 4;
    const int tx = blockIdx.x % tpr;
    const int ty = blockIdx.x / tpr;
    const int x0 = tx << 4;
    const int y0 = ty << 4;
    const int HW = H * W;

    int soff[3];
#pragma unroll
    for (int t = 0; t < 3; ++t) {
        int s = tid + t * 512;
        int item = s >> 2, u = s & 3;
        int row = item / 18, col = item - row * 18;
        int y = y0 + row - 1, x = x0 + col - 1;
        soff[t] = (s < 1296 && y >= 0 && y < H && x >= 0 && x < W)
                      ? ((n * HW + y * W + x) * inCst + u * 8) : -1;
    }

    f32x4 acc[4][4];
#pragma unroll
    for (int m = 0; m < 4; ++m)
#pragma unroll
        for (int nf = 0; nf < 4; ++nf)
            acc[m][nf] = (f32x4){0.f, 0.f, 0.f, 0.f};

    const size_t tstride = (size_t)CC * 4 * Cout * 8;

    {
        const _Float16* src = (const _Float16*)inv;
#pragma unroll
        for (int t = 0; t < 3; ++t) {
            int s = tid + t * 512;
            if (s < 1296 && soff[t] < 0) {
                *reinterpret_cast<f16x8*>(&Xs[s * 8]) = (f16x8){};
                *reinterpret_cast<f16x8*>(&Xs[(1344 + s) * 8]) = (f16x8){};
            }
        }
#pragma unroll
        for (int t = 0; t < 3; ++t) {
            int s = tid + t * 512;
            if (s < 1296 && soff[t] >= 0)
                gll16(src + soff[t], &Xs[(t * 512 + (tid & ~63)) * 8]);
        }
    }
    __syncthreads();

    int bsel = 0;
    for (int cc = 0; cc < CC; ++cc) {
        if (cc + 1 < CC) {
            const _Float16* src = (const _Float16*)inv;
#pragma unroll
            for (int t = 0; t < 3; ++t) {
                int s = tid + t * 512;
                if (s < 1296 && soff[t] >= 0)
                    gll16(src + soff[t] + (cc + 1) * 32,
                          &Xs[((bsel ^ 1) * 1344 + t * 512 + (tid & ~63)) * 8]);
            }
        }
        {
            const int xbase = bsel * 1344;
            const _Float16* wb = wp + (((size_t)cc * 4 + lu) * Cout + co0 + waveco + lm) * 8;
#pragma unroll
            for (int tap = 0; tap < 9; ++tap) {
                const int dy = tap / 3, dx = tap % 3;
                const _Float16* wt = wb + (size_t)tap * tstride;
                f16x8 a[4], b[4];
#pragma unroll
                for (int m = 0; m < 4; ++m)
                    a[m] = *reinterpret_cast<const f16x8*>(wt + m * 128);
#pragma unroll
                for (int nf = 0; nf < 4; ++nf) {
                    int slot = ((wrow + nf + dy) * 18 + lm + dx) * 4 + lu;
                    b[nf] = *reinterpret_cast<const f16x8*>(&Xs[(xbase + slot) * 8]);
                }
#pragma unroll
                for (int m = 0; m < 4; ++m)
#pragma unroll
                    for (int nf = 0; nf < 4; ++nf)
                        acc[m][nf] = __builtin_amdgcn_mfma_f32_16x16x32_f16(a[m], b[nf], acc[m][nf], 0, 0, 0);
            }
        }
        __syncthreads();
        bsel ^= 1;
    }

    const int xE = x0 + lm;
    const size_t nHW = (size_t)n * HW;
#pragma unroll
    for (int nf = 0; nf < 4; ++nf) {
        const int y = y0 + wrow + nf;
        float mv = 1.f;
        if (useMask) mv = (msk[nHW + y * W + xE] > 0) ? 1.f : 0.f;
        const size_t pixo = (nHW + (size_t)y * W + xE) * outCst;
#pragma unroll
        for (int m = 0; m < 4; ++m) {
            const int cb = co0 + waveco + m * 16 + lu * 4;
            const f32x4 bv = *reinterpret_cast<const f32x4*>(bias + cb);
            if (OUTMODE == 0) {
                f16x4 h;
#pragma unroll
                for (int r = 0; r < 4; ++r)
                    h[r] = (_Float16)(fmaxf(acc[m][nf][r] + bv[r], 0.f) * mv);
                *reinterpret_cast<f16x4*>((_Float16*)outp + pixo + cb) = h;
            } else if (OUTMODE == 1) {
                f32x4 v;
#pragma unroll
                for (int r = 0; r < 4; ++r)
                    v[r] = fmaxf(acc[m][nf][r] + bv[r], 0.f);
                *reinterpret_cast<f32x4*>((float*)outp + pixo + cb) = v;
            } else {
                f32x4 old = *reinterpret_cast<const f32x4*>((float*)outp + pixo + cb);
#pragma unroll
                for (int r = 0; r < 4; ++r)
                    old[r] += fmaxf(acc[m][nf][r] + bv[r], 0.f);
                *reinterpret_cast<f32x4*>((float*)outp + pixo + cb) = old;
            }
        }
    }
}

// ---------------------------------------------------------------------------
// DENSE conv as LDS-staged GEMM tile (p2 + comb @128^2). Tile: 256 co x
// 256 px (16x16); 512 thr, 8 waves = 2 co-halves x 4 px-quarters.
// K = 9*CINP tap-major, step 64, cb-major (L2-hot), dbuf 128KB.
// ---------------------------------------------------------------------------
template<int CINP, int MASK>
__global__ __launch_bounds__(512, 1)
void gemm_dense_kernel(const _Float16* __restrict__ in,
                       const _Float16* __restrict__ wpk,
                       const float* __restrict__ bias,
                       const int* __restrict__ fg,
                       _Float16* __restrict__ outp, int outCst,
                       const _Float16* __restrict__ zpage)
{
    constexpr int SPT = CINP / 64;
    __shared__ __attribute__((aligned(16))) char ldsb[2 * 65536];  // 128 KB

    const int job = blockIdx.x;        // 0..255
    const int xcd = job & 7;
    const int idx = job >> 3;          // 0..31
    const int img = idx >> 3;          // 0..3
    const int tile = xcd * 8 + (idx & 7);
    const int x0 = (tile & 7) << 4;
    const int y0 = (tile >> 3) << 4;

    const int tid = threadIdx.x;
    const int lane = tid & 63;
    const int wave = tid >> 6;
    const int lm = lane & 15;
    const int lu = lane >> 4;
    const int wco = (wave & 1) * 128;
    const int wpx = (wave >> 1) * 64;

    const _Float16* bsrc = in + (size_t)img * 16384 * CINP;

    const _Float16* bptr[4];
    unsigned long long inbm = 0;
    int dstA[4], dstB[4];
#pragma unroll
    for (int s = 0; s < 4; ++s) {
        const int row = s * 64 + (tid >> 3);   // 0..255
        const int kc = (tid & 7) ^ (row & 7);
        const int y = y0 + (row >> 4);
        const int x = x0 + (row & 15);
        bptr[s] = bsrc + (size_t)(y * 128 + x) * CINP + kc * 8;
#pragma unroll
        for (int tap = 0; tap < 9; ++tap) {
            const int yy = y + tap / 3 - 1;
            const int xx = x + tap % 3 - 1;
            if ((unsigned)yy < 128u && (unsigned)xx < 128u)
                inbm |= 1ull << (s * 9 + tap);
        }
        dstA[s] = (s * 512 + (tid & ~63)) * 16;
        dstB[s] = 32768 + (s * 512 + (tid & ~63)) * 16;
    }

    auto STAGE = [&](int t, int bufByte) {
        const _Float16* as = wpk + (size_t)t * 16384;
#pragma unroll
        for (int s = 0; s < 4; ++s)
            gll16(as + (size_t)(s * 512 + tid) * 8, ldsb + bufByte + dstA[s]);
        const int tap = t / SPT;
        const int ci0 = (t % SPT) * 64;
        const int delta = ((tap / 3 - 1) * 128 + (tap % 3 - 1)) * CINP + ci0;
#pragma unroll
        for (int s = 0; s < 4; ++s) {
            const bool ok = (inbm >> (s * 9 + tap)) & 1ull;
            const _Float16* src = ok ? (bptr[s] + delta) : zpage;
            gll16(src, ldsb + bufByte + dstB[s]);
        }
    };

    f32x4 acc[8][4];
#pragma unroll
    for (int m = 0; m < 8; ++m)
#pragma unroll
        for (int n = 0; n < 4; ++n)
            acc[m][n] = (f32x4){0.f, 0.f, 0.f, 0.f};

    STAGE(0, 0);
    __syncthreads();

    int bsel = 0;
    for (int cb = 0; cb < SPT; ++cb) {
        for (int tap = 0; tap < 9; ++tap) {
            if (tap < 8) STAGE((tap + 1) * SPT + cb, (bsel ^ 1) * 65536);
            else if (cb + 1 < SPT) STAGE(cb + 1, (bsel ^ 1) * 65536);
            const int ab = bsel * 65536;
#pragma unroll
            for (int s = 0; s < 2; ++s) {
                f16x8 bfr[4];
#pragma unroll
                for (int n = 0; n < 4; ++n) {
                    const int row = wpx + n * 16 + lm;
                    const int ch = (s * 4 + lu) ^ (row & 7);
                    bfr[n] = *reinterpret_cast<const f16x8*>(ldsb + ab + 32768 + row * 128 + ch * 16);
                }
#pragma unroll
                for (int m = 0; m < 8; ++m) {
                    const int row = wco + m * 16 + lm;
                    const int ch = (s * 4 + lu) ^ (row & 7);
                    const f16x8 afr = *reinterpret_cast<const f16x8*>(ldsb + ab + row * 128 + ch * 16);
#pragma unroll
                    for (int n = 0; n < 4; ++n)
                        acc[m][n] = __builtin_amdgcn_mfma_f32_16x16x32_f16(afr, bfr[n], acc[m][n], 0, 0, 0);
                }
            }
            __syncthreads();
            bsel ^= 1;
        }
    }

    const int base = img * 16384;
#pragma unroll
    for (int n = 0; n < 4; ++n) {
        const int px = wpx + n * 16 + lm;
        const int y = y0 + (px >> 4), x = x0 + (px & 15);
        float mv = 1.f;
        if (MASK) mv = (fg[base + y * 128 + x] > 0) ? 1.f : 0.f;
        _Float16* pp = outp + ((size_t)base + y * 128 + x) * outCst + wco;
#pragma unroll
        for (int m = 0; m < 8; ++m) {
            const f32x4 bv = *reinterpret_cast<const f32x4*>(bias + wco + m * 16 + lu * 4);
            f16x4 h;
#pragma unroll
            for (int rr = 0; rr < 4; ++rr)
                h[rr] = (_Float16)(fmaxf(acc[m][n][rr] + bv[rr], 0.f) * mv);
            *reinterpret_cast<f16x4*>(pp + m * 16 + lu * 4) = h;
        }
    }
}

// ---------------------------------------------------------------------------
// SPARSE head conv as gather-GEMM over active pixels (R14 geometry, best
// measured: 171us/layer, MfmaUtil 35%). Tile 256co(gy half) x 320 listed px;
// 512 thr, 8 waves = 2 co-halves x 4 px-grp of 80 (5 n-frags). K step 64,
// cb-major, dbuf 144KB (A 32K + B 40K), launch_bounds(512,1) -- VGPR caps
// (R9/R15: spill) and smaller tiles (R16: less compute/barrier) both lose.
// ---------------------------------------------------------------------------
template<int CIN>
__global__ __launch_bounds__(512, 1)
void gemm_head_kernel(const _Float16* __restrict__ in,
                      const _Float16* __restrict__ wpk,
                      const float* __restrict__ bias,
                      const int* __restrict__ list,
                      _Float16* __restrict__ outp,
                      const _Float16* __restrict__ zpage)
{
    constexpr int SPT = CIN / 64;
    __shared__ __attribute__((aligned(16))) char ldsb[2 * 73728];  // 144 KB

    const int job = blockIdx.x;        // 0..255
    const int xcd = job & 7;
    const int r8 = job >> 3;           // 0..31
    const int tile = xcd * 16 + (r8 >> 1);
    const int gy = r8 & 1;
    if (list[tile * 320] < 0) return;

    const int tid = threadIdx.x;
    const int lane = tid & 63;
    const int wave = tid >> 6;
    const int lm = lane & 15;
    const int lu = lane >> 4;
    const int wco = (wave & 1) * 128;
    const int g80 = (wave >> 1) * 80;
    const int co0 = gy * 256;

    const _Float16* bptr[5];
    unsigned long long inbm = 0;
    int dstA[4], dstB[5];
#pragma unroll
    for (int s = 0; s < 5; ++s) {
        const int row = s * 64 + (tid >> 3);
        const int kc = (tid & 7) ^ (row & 7);
        const int entry = list[tile * 320 + row];
        bptr[s] = zpage;
        if (entry >= 0) {
            const int y = (entry >> 7) & 127;
            const int x = entry & 127;
            bptr[s] = in + (size_t)entry * CIN + kc * 8;
#pragma unroll
            for (int tap = 0; tap < 9; ++tap) {
                const int yy = y + tap / 3 - 1;
                const int xx = x + tap % 3 - 1;
                if ((unsigned)yy < 128u && (unsigned)xx < 128u)
                    inbm |= 1ull << (s * 9 + tap);
            }
        }
        dstB[s] = 32768 + (s * 512 + (tid & ~63)) * 16;
    }
#pragma unroll
    for (int s = 0; s < 4; ++s) dstA[s] = (s * 512 + (tid & ~63)) * 16;

    auto STAGE = [&](int t, int bufByte) {
        const _Float16* as = wpk + (size_t)(t * 2 + gy) * 16384;
#pragma unroll
        for (int s = 0; s < 4; ++s)
            gll16(as + (size_t)(s * 512 + tid) * 8, ldsb + bufByte + dstA[s]);
        const int tap = t / SPT;
        const int ci0 = (t % SPT) * 64;
        const int delta = ((tap / 3 - 1) * 128 + (tap % 3 - 1)) * CIN + ci0;
#pragma unroll
        for (int s = 0; s < 5; ++s) {
            const bool ok = (inbm >> (s * 9 + tap)) & 1ull;
            const _Float16* src = ok ? (bptr[s] + delta) : zpage;
            gll16(src, ldsb + bufByte + dstB[s]);
        }
    };

    f32x4 acc[8][5];
#pragma unroll
    for (int m = 0; m < 8; ++m)
#pragma unroll
        for (int n = 0; n < 5; ++n)
            acc[m][n] = (f32x4){0.f, 0.f, 0.f, 0.f};

    STAGE(0, 0);
    __syncthreads();

    int bsel = 0;
    for (int cb = 0; cb < SPT; ++cb) {
        for (int tap = 0; tap < 9; ++tap) {
            if (tap < 8) STAGE((tap + 1) * SPT + cb, (bsel ^ 1) * 73728);
            else if (cb + 1 < SPT) STAGE(cb + 1, (bsel ^ 1) * 73728);
            const int ab = bsel * 73728;
#pragma unroll
            for (int s = 0; s < 2; ++s) {
                f16x8 bfr[5];
#pragma unroll
                for (int n = 0; n < 5; ++n) {
                    const int row = g80 + n * 16 + lm;
                    const int ch = (s * 4 + lu) ^ (row & 7);
                    bfr[n] = *reinterpret_cast<const f16x8*>(ldsb + ab + 32768 + row * 128 + ch * 16);
                }
#pragma unroll
                for (int m = 0; m < 8; ++m) {
                    const int row = wco + m * 16 + lm;
                    const int ch = (s * 4 + lu) ^ (row & 7);
                    const f16x8 afr = *reinterpret_cast<const f16x8*>(ldsb + ab + row * 128 + ch * 16);
#pragma unroll
                    for (int n = 0; n < 5; ++n)
                        acc[m][n] = __builtin_amdgcn_mfma_f32_16x16x32_f16(afr, bfr[n], acc[m][n], 0, 0, 0);
                }
            }
            __syncthreads();
            bsel ^= 1;
        }
    }

#pragma unroll
    for (int n = 0; n < 5; ++n) {
        const int entry = list[tile * 320 + g80 + n * 16 + lm];
        if (entry < 0) continue;
        _Float16* pp = outp + (size_t)entry * 512 + co0 + wco;
#pragma unroll
        for (int m = 0; m < 8; ++m) {
            const f32x4 bv = *reinterpret_cast<const f32x4*>(bias + co0 + wco + m * 16 + lu * 4);
            f16x4 h;
#pragma unroll
            for (int rr = 0; rr < 4; ++rr)
                h[rr] = (_Float16)fmaxf(acc[m][n][rr] + bv[rr], 0.f);
            *reinterpret_cast<f16x4*>(pp + m * 16 + lu * 4) = h;
        }
    }
}

// ---------------------------------------------------------------------------
// fp16 NHWC 2x bilinear upsample (align_corners=False -> clamped 0.75/0.25).
// ---------------------------------------------------------------------------
__global__ void up2h_kernel(const _Float16* __restrict__ in, _Float16* __restrict__ out,
                            int Hin, int Win)
{
    const int Wout = Win << 1, Hout = Hin << 1;
    const int lw = __ffs(Wout) - 1, lh = __ffs(Hout) - 1;
    int i = blockIdx.x * THREADS + threadIdx.x;
    if (i >= 4 * Hout * Wout * 32) return;
    int u = i & 31;
    int p = i >> 5;
    int x = p & (Wout - 1);
    int y = (p >> lw) & (Hout - 1);
    int n = p >> (lw + lh);
    int iy = y >> 1, ix = x >> 1;
    int y2 = (y & 1) ? min(iy + 1, Hin - 1) : max(iy - 1, 0);
    int x2 = (x & 1) ? min(ix + 1, Win - 1) : max(ix - 1, 0);
    const _Float16* base = in + ((size_t)n * Hin * Win) * 256 + u * 8;
    f16x8 v00 = *reinterpret_cast<const f16x8*>(base + (iy * Win + ix) * 256);
    f16x8 v01 = *reinterpret_cast<const f16x8*>(base + (iy * Win + x2) * 256);
    f16x8 v10 = *reinterpret_cast<const f16x8*>(base + (y2 * Win + ix) * 256);
    f16x8 v11 = *reinterpret_cast<const f16x8*>(base + (y2 * Win + x2) * 256);
    f16x8 o;
#pragma unroll
    for (int j = 0; j < 8; ++j) {
        float v = 0.5625f * (float)v00[j] + 0.1875f * ((float)v01[j] + (float)v10[j])
                + 0.0625f * (float)v11[j];
        o[j] = (_Float16)v;
    }
    *reinterpret_cast<f16x8*>(out + (((size_t)n * Hout * Wout) + y * Wout + x) * 256 + u * 8) = o;
}

// fp32 NHWC 64^2 t64sum -> 128^2 upsample-ADD into fp16 Xch (stride 320, ch 0..255).
__global__ void up2addh_kernel(const float* __restrict__ in, _Float16* __restrict__ Xch)
{
    int i = blockIdx.x * THREADS + threadIdx.x;
    if (i >= 4 * 16384 * 32) return;
    int u = i & 31;
    int p = i >> 5;
    int x = p & 127;
    int y = (p >> 7) & 127;
    int n = p >> 14;
    int iy = y >> 1, ix = x >> 1;
    int y2 = (y & 1) ? min(iy + 1, 63) : max(iy - 1, 0);
    int x2 = (x & 1) ? min(ix + 1, 63) : max(ix - 1, 0);
    const float* base = in + ((size_t)n * 4096) * 256 + u * 8;
    f32x8 v00 = *reinterpret_cast<const f32x8*>(base + (iy * 64 + ix) * 256);
    f32x8 v01 = *reinterpret_cast<const f32x8*>(base + (iy * 64 + x2) * 256);
    f32x8 v10 = *reinterpret_cast<const f32x8*>(base + (y2 * 64 + ix) * 256);
    f32x8 v11 = *reinterpret_cast<const f32x8*>(base + (y2 * 64 + x2) * 256);
    _Float16* dst = Xch + ((size_t)n * 16384 + y * 128 + x) * 320 + u * 8;
    f16x8 d = *reinterpret_cast<const f16x8*>(dst);
#pragma unroll
    for (int j = 0; j < 8; ++j)
        d[j] = (_Float16)((float)d[j] + 0.5625f * v00[j]
               + 0.1875f * (v01[j] + v10[j]) + 0.0625f * v11[j]);
    *reinterpret_cast<f16x8*>(dst) = d;
}

// Coords into fp16 Xch (stride 320) channels 256..259; zero channels 260..319.
__global__ void coords2h_kernel(const float* __restrict__ rel, const float* __restrict__ abs_,
                                _Float16* __restrict__ Xch)
{
    int i = blockIdx.x * THREADS + threadIdx.x;
    if (i >= 4 * 16384) return;
    int px = i & 16383;
    int n = i >> 14;
    _Float16* dst = Xch + ((size_t)n * 16384 + px) * 320 + 256;
    f16x8 v0 = (f16x8){};
    v0[0] = (_Float16)rel[((size_t)n * 2 + 0) * 16384 + px];
    v0[1] = (_Float16)rel[((size_t)n * 2 + 1) * 16384 + px];
    v0[2] = (_Float16)abs_[((size_t)n * 2 + 0) * 16384 + px];
    v0[3] = (_Float16)abs_[((size_t)n * 2 + 1) * 16384 + px];
    *reinterpret_cast<f16x8*>(dst) = v0;
#pragma unroll
    for (int b = 1; b < 8; ++b)
        *reinterpret_cast<f16x8*>(dst + b * 8) = (f16x8){};
}

// 1x1 predictor: NHWC fp16 [n][16384][512] -> NCHW fp32 [n][75][16384].
__global__ __launch_bounds__(256)
void predh_kernel(const _Float16* __restrict__ in, const float* __restrict__ w,
                  const float* __restrict__ bias, float* __restrict__ out)
{
    __shared__ _Float16 lw[25 * 512];
    const int co0 = blockIdx.y * 25;
    const int n = blockIdx.z;
    for (int idx = threadIdx.x; idx < 25 * 512; idx += 256)
        lw[idx] = (_Float16)w[(size_t)(co0 + idx / 512) * 512 + (idx & 511)];
    __syncthreads();
    int px = blockIdx.x * 256 + threadIdx.x;
    const _Float16* ip = in + ((size_t)n * 16384 + px) * 512;
    float acc[25];
#pragma unroll
    for (int j = 0; j < 25; ++j) acc[j] = bias[co0 + j];
    for (int g = 0; g < 64; ++g) {
        union { f16x8 v; f16x2 p[4]; } xv;
        xv.v = *reinterpret_cast<const f16x8*>(ip + g * 8);
#pragma unroll
        for (int j = 0; j < 25; ++j) {
            union { f16x8 v; f16x2 p[4]; } wv;
            wv.v = *reinterpret_cast<const f16x8*>(&lw[j * 512 + g * 8]);
#if __has_builtin(__builtin_amdgcn_fdot2)
#pragma unroll
            for (int k = 0; k < 4; ++k)
                acc[j] = __builtin_amdgcn_fdot2(xv.p[k], wv.p[k], acc[j], false);
#else
#pragma unroll
            for (int k = 0; k < 8; ++k)
                acc[j] = fmaf((float)xv.v[k], (float)wv.v[k], acc[j]);
#endif
        }
    }
    float* op = out + ((size_t)n * 75) * 16384 + px;
#pragma unroll
    for (int j = 0; j < 25; ++j)
        op[(size_t)(co0 + j) * 16384] = acc[j];
}

extern "C" void kernel_launch(void* const* d_in, const int* in_sizes, int n_in,
                              void* d_out, int out_size, void* d_ws, size_t ws_size,
                              hipStream_t stream)
{
    const float* p2   = (const float*)d_in[0];
    const float* p3   = (const float*)d_in[1];
    const float* p4   = (const float*)d_in[2];
    const float* p5   = (const float*)d_in[3];
    const float* rel  = (const float*)d_in[4];
    const float* abs_ = (const float*)d_in[5];
    const int*   fg   = (const int*)d_in[6];
    const float* w_p2_0 = (const float*)d_in[7];
    const float* b_p2_0 = (const float*)d_in[8];
    const float* w_p3_0 = (const float*)d_in[9];
    const float* b_p3_0 = (const float*)d_in[10];
    const float* w_p4_0 = (const float*)d_in[11];
    const float* b_p4_0 = (const float*)d_in[12];
    const float* w_p4_1 = (const float*)d_in[13];
    const float* b_p4_1 = (const float*)d_in[14];
    const float* w_p5_0 = (const float*)d_in[15];
    const float* b_p5_0 = (const float*)d_in[16];
    const float* w_p5_1 = (const float*)d_in[17];
    const float* b_p5_1 = (const float*)d_in[18];
    const float* w_p5_2 = (const float*)d_in[19];
    const float* b_p5_2 = (const float*)d_in[20];
    const float* comb_w = (const float*)d_in[21];
    const float* comb_b = (const float*)d_in[22];
    const float* head_w0 = (const float*)d_in[23];
    const float* head_b0 = (const float*)d_in[24];
    const float* head_w  = (const float*)d_in[25];
    const float* head_b  = (const float*)d_in[26];
    const float* pred_w  = (const float*)d_in[27];
    const float* pred_b  = (const float*)d_in[28];

    // Workspace layout (float offsets). Total 58,704,896 floats = 234.8 MB.
    float* ws = (float*)d_ws;
    _Float16* Xch     = (_Float16*)ws;                       // 10,485,760 fl as f16 (stride 320)
    _Float16* pingA   = (_Float16*)ws;                       // aliases Xch (dead after comb)
    _Float16* pingB   = (_Float16*)(ws + 18874368);          // 16,777,216 fl
    float*    regD    = ws + 35651584;                       //  8,388,608 fl
    _Float16* p2h     = (_Float16*)regD;
    _Float16* combOut = (_Float16*)regD;
    float*    t64sum  = regD;
    _Float16* t64b    = (_Float16*)(regD + 4194304);
    _Float16* t64c    = (_Float16*)(regD + 5242880);
    _Float16* t32a    = (_Float16*)(regD + 6291456);
    _Float16* t32b    = (_Float16*)(regD + 6553600);
    _Float16* t32c    = (_Float16*)(regD + 6815744);
    _Float16* t16a    = (_Float16*)(regD + 7077888);
    _Float16* p3h     = (_Float16*)(ws + 44040192);          //  2,097,152 fl
    _Float16* p4h     = (_Float16*)(ws + 46137344);          //    524,288 fl
    _Float16* p5h     = (_Float16*)(ws + 46661632);          //    131,072 fl
    _Float16* wpScale = (_Float16*)(ws + 46792704);          //  2,654,208 fl (8 x 663,552 f16)
    float*    zpage   = ws + 49446912;                       //      1,024 fl (4 KB zeros)
    _Float16* wpH0    = (_Float16*)(ws + 49447936);          //    589,824 fl (1,179,648 f16)
    _Float16* wpH     = (_Float16*)(ws + 50037760);          //  8,257,536 fl (7 x 2,359,296 f16)
    int*      actList = (int*)(ws + 58295296);               //     40,960 ints
    _Float16* wpComb  = (_Float16*)(ws + 58336256);          //    368,640 fl (737,280 f16)
    _Float16* wpDp2   = wpScale;                             // dense p2 pack reuses slot 0

    auto wpS = [&](int i) { return wpScale + (size_t)i * 663552; };

    auto convu = [&](const void* in, const _Float16* wpk, const float* bs, void* outp,
                     int mode, int Cout, int H, int W,
                     int inCst, int outCst) {
        dim3 grid((W / 16) * (H / 16), Cout / 128, 4);
        dim3 blk(512);
        if (mode == 0)
            convu_kernel<0, 0, 8><<<grid, blk, 0, stream>>>(in, wpk, bs, fg, outp, Cout, H, W, inCst, outCst, 0);
        else if (mode == 1)
            convu_kernel<0, 1, 8><<<grid, blk, 0, stream>>>(in, wpk, bs, fg, outp, Cout, H, W, inCst, outCst, 0);
        else
            convu_kernel<0, 2, 8><<<grid, blk, 0, stream>>>(in, wpk, bs, fg, outp, Cout, H, W, inCst, outCst, 0);
    };
    auto up2h = [&](const _Float16* in, _Float16* out, int Hin, int Win) {
        int total = 4 * (Hin * 2) * (Win * 2) * 32;
        up2h_kernel<<<dim3((total + THREADS - 1) / THREADS), dim3(THREADS), 0, stream>>>(
            in, out, Hin, Win);
    };

    // ---- batched packs + zero-page + compaction + batched transposes ----
    zerows_kernel<<<dim3(4), dim3(THREADS), 0, stream>>>(zpage);
    compact_kernel<<<dim3(1), dim3(1024), 0, stream>>>(fg, actList);
    pack_scale_all_kernel<<<dim3(36, 8), dim3(THREADS), 0, stream>>>(
        w_p2_0, w_p3_0, w_p4_0, w_p4_1, w_p5_0, w_p5_1, w_p5_2, comb_w, wpScale);
    pack_wdense_kernel<<<dim3(288), dim3(THREADS), 0, stream>>>(w_p2_0, wpDp2, 256, 256);
    pack_wdense_kernel<<<dim3(360), dim3(THREADS), 0, stream>>>(comb_w, wpComb, 260, 320);
    pack_whead_all_kernel<<<dim3(1152, 8), dim3(THREADS), 0, stream>>>(
        head_w0, head_w, wpH0, wpH);
    t_all_kernel<<<dim3(256, 8, 16), dim3(256), 0, stream>>>(
        p2, p3, p4, p5, p2h, p3h, p4h, p5h);

    // ---- p2 scale head -> Xch (fp16 NHWC-320, dense GEMM tile), coords ----
    gemm_dense_kernel<256, 0><<<dim3(256), dim3(512), 0, stream>>>(
        p2h, wpDp2, b_p2_0, fg, Xch, 320, (const _Float16*)zpage);
    coords2h_kernel<<<dim3(256), dim3(THREADS), 0, stream>>>(rel, abs_, Xch);

    // ---- p3 -> t64sum (fp32 write) ----
    convu(p3h, wpS(1), b_p3_0, t64sum, 1, 256, 64, 64, 256, 256);

    // ---- p4 chain: conv32 -> up -> conv64 (fp32 add into t64sum) ----
    convu(p4h, wpS(2), b_p4_0, t32a, 0, 256, 32, 32, 256, 256);
    up2h(t32a, t64b, 32, 32);
    convu(t64b, wpS(3), b_p4_1, t64sum, 2, 256, 64, 64, 256, 256);

    // ---- p5 chain: conv16 -> up -> conv32 -> up -> conv64 (fp32 add) ----
    convu(p5h, wpS(4), b_p5_0, t16a, 0, 256, 16, 16, 256, 256);
    up2h(t16a, t32b, 16, 16);
    convu(t32b, wpS(5), b_p5_1, t32c, 0, 256, 32, 32, 256, 256);
    up2h(t32c, t64c, 32, 32);
    convu(t64c, wpS(6), b_p5_2, t64sum, 2, 256, 64, 64, 256, 256);

    // ---- single upsample-add of merged 64^2 sum into fp16 Xch (stride 320) ----
    up2addh_kernel<<<dim3(8192), dim3(THREADS), 0, stream>>>(t64sum, Xch);

    // ---- comb conv (Xch fp16 NHWC-320 -> combOut fp16 NHWC-256), dense GEMM ----
    gemm_dense_kernel<320, 1><<<dim3(256), dim3(512), 0, stream>>>(
        Xch, wpComb, comb_b, fg, combOut, 256, (const _Float16*)zpage);

    // ---- zero ping buffers (Xch dead now; inactive rows must be exactly 0) ----
    zero2_kernel<<<dim3(4096), dim3(THREADS), 0, stream>>>(pingA, pingB);

    // ---- head chain: sparse gather-GEMM convs over active pixels ----
    gemm_head_kernel<256><<<dim3(256), dim3(512), 0, stream>>>(
        combOut, wpH0, head_b0, actList, pingA, (const _Float16*)zpage);
    {
        const _Float16* s = pingA;
        _Float16* d = pingB;
        for (int i = 0; i < 7; ++i) {
            gemm_head_kernel<512><<<dim3(256), dim3(512), 0, stream>>>(
                s, wpH + (size_t)i * 2359296, head_b + (size_t)i * 512, actList, d,
                (const _Float16*)zpage);
            _Float16* tmp = (_Float16*)s; s = d; d = tmp;
        }
    }

    // ---- predictor (reads pingB), batched ----
    predh_kernel<<<dim3(64, 3, 4), dim3(256), 0, stream>>>(pingB, pred_w, pred_b, (float*)d_out);
}